// Round 13
// baseline (1080.652 us; speedup 1.0000x reference)
//
#include <hip/hip_runtime.h>
#include <math.h>

typedef __attribute__((ext_vector_type(8))) short bf16x8;   // 8 bf16 in 4 VGPRs
typedef __attribute__((ext_vector_type(4))) float f32x4;
typedef unsigned short u16;

__device__ __forceinline__ u16 f2bf(float f) {
  unsigned u = __float_as_uint(f);
  return (u16)((u + 0x7FFFu + ((u >> 16) & 1u)) >> 16);   // RNE
}
__device__ __forceinline__ float bf2f(u16 h) {
  return __uint_as_float(((unsigned)h) << 16);
}
__device__ __forceinline__ uint2 pack4(const f32x4 v) {
  uint2 r;
  r.x = (unsigned)f2bf(v[0]) | ((unsigned)f2bf(v[1]) << 16);
  r.y = (unsigned)f2bf(v[2]) | ((unsigned)f2bf(v[3]) << 16);
  return r;
}

__device__ __forceinline__ void gload16(const u16* g, void* lds) {
  __builtin_amdgcn_global_load_lds(
      (const __attribute__((address_space(1))) unsigned int*)g,
      (__attribute__((address_space(3))) unsigned int*)lds, 16, 0, 0);
}

// ---------------------------------------------------------------------------
// MFMA core (proven): 128x128 tile, BK=32, 256 threads (4 waves = 2x2
// quadrants of 4x4 16x16x32 fragments). K mult of 32; padded buffers.
// acc[i][j] fragment: row (M) = wm*64+i*16+(l>>4)*4+r, col (N) = wn*64+j*16+(l&15)
// ---------------------------------------------------------------------------
__device__ __forceinline__ void mfma_core(
    const u16* __restrict__ A, int lda,
    const u16* __restrict__ B, int ldb,
    int K, f32x4 (&acc)[4][4], u16* As, u16* Bs)
{
  const int tid = threadIdx.x;
  const int l = tid & 63, w = tid >> 6;
  const int srow = w * 16 + (l >> 2);
  const int kel  = (l & 3) * 8;
  char* AsB = (char*)As + w * 1024;
  char* BsB = (char*)Bs + w * 1024;
  const u16* Ap  = A + (size_t)srow * lda + kel;
  const u16* Ap2 = A + (size_t)(srow + 64) * lda + kel;
  const u16* Bp  = B + (size_t)srow * ldb + kel;
  const u16* Bp2 = B + (size_t)(srow + 64) * ldb + kel;
  const int wm = w >> 1, wn = w & 1;
  const int aoff = (wm * 64 + (l & 15)) * 32 + (l >> 4) * 8;
  const int boff = (wn * 64 + (l & 15)) * 32 + (l >> 4) * 8;
  for (int kb = 0; kb < K; kb += 32) {
    __syncthreads();
    gload16(Ap + kb,  AsB);
    gload16(Ap2 + kb, AsB + 4096);
    gload16(Bp + kb,  BsB);
    gload16(Bp2 + kb, BsB + 4096);
    __syncthreads();
    bf16x8 av[4], bv[4];
#pragma unroll
    for (int i = 0; i < 4; ++i) {
      av[i] = *(const bf16x8*)(As + aoff + i * 16 * 32);
      bv[i] = *(const bf16x8*)(Bs + boff + i * 16 * 32);
    }
#pragma unroll
    for (int i = 0; i < 4; ++i)
#pragma unroll
      for (int j = 0; j < 4; ++j)
        acc[i][j] = __builtin_amdgcn_mfma_f32_16x16x32_bf16(av[i], bv[j], acc[i][j], 0, 0, 0);
  }
}

// ---------------------------------------------------------------------------
// One-shot pad/convert of all inputs (11 segments, hardcoded boundaries).
// ---------------------------------------------------------------------------
__global__ __launch_bounds__(256) void k_cvt(
    const float* __restrict__ eall,
    const float* __restrict__ Wq1, const float* __restrict__ Wq2,
    const float* __restrict__ Wq3, const float* __restrict__ Wq4,
    const float* __restrict__ Wk, const float* __restrict__ Wv,
    const float* __restrict__ Wo1, const float* __restrict__ Wo2,
    const float* __restrict__ Wo3, const float* __restrict__ Wo4,
    u16* __restrict__ embA, u16* __restrict__ WkB, u16* __restrict__ WvB,
    u16* __restrict__ WqB, u16* __restrict__ WoB)
{
  long long idx = (long long)blockIdx.x * 256 + threadIdx.x;
  const float* src; u16* dst; int srcR, dstR, C; long long stride, off, loc;
  if (idx < 6881280LL)       { loc = idx;               src=eall; dst=embA; srcR=196; dstR=224;  C=960; stride=215040; off=0; }
  else if (idx < 10813440LL) { loc = idx - 6881280LL;   src=Wk;   dst=WkB;  srcR=960; dstR=1024; C=960; stride=983040; off=0; }
  else if (idx < 14745600LL) { loc = idx - 10813440LL;  src=Wv;   dst=WvB;  srcR=960; dstR=1024; C=960; stride=983040; off=0; }
  else if (idx < 14778368LL) { loc = idx - 14745600LL;  src=Wq1;  dst=WqB;  srcR=64;  dstR=128;  C=64;  stride=352256; off=0; }
  else if (idx < 14843904LL) { loc = idx - 14778368LL;  src=Wq2;  dst=WqB;  srcR=128; dstR=128;  C=128; stride=352256; off=8192; }
  else if (idx < 15106048LL) { loc = idx - 14843904LL;  src=Wq3;  dst=WqB;  srcR=256; dstR=256;  C=256; stride=352256; off=24576; }
  else if (idx < 16154624LL) { loc = idx - 15106048LL;  src=Wq4;  dst=WqB;  srcR=512; dstR=512;  C=512; stride=352256; off=90112; }
  else if (idx < 16162816LL) { loc = idx - 16154624LL;  src=Wo1;  dst=WoB;  srcR=64;  dstR=128;  C=64;  stride=0; off=0; }
  else if (idx < 16179200LL) { loc = idx - 16162816LL;  src=Wo2;  dst=WoB;  srcR=128; dstR=128;  C=128; stride=0; off=8192; }
  else if (idx < 16244736LL) { loc = idx - 16179200LL;  src=Wo3;  dst=WoB;  srcR=256; dstR=256;  C=256; stride=0; off=24576; }
  else if (idx < 16506880LL) { loc = idx - 16244736LL;  src=Wo4;  dst=WoB;  srcR=512; dstR=512;  C=512; stride=0; off=90112; }
  else return;
  const long long per = (long long)dstR * C;
  const int g = (int)(loc / per);
  const int r2 = (int)(loc % per);
  const int rr = r2 / C, c = r2 - rr * C;
  const float v = (rr < srcR) ? src[((long long)g * srcR + rr) * C + c] : 0.f;
  dst[g * stride + off + (long long)rr * C + c] = f2bf(v);
}

// Kt[h][o 1024][tok NB]: A = embA (M=tok), B = WkB (N=o); r -> tok (contig).
__global__ __launch_bounds__(256) void k_kt(const u16* __restrict__ embA,
    const u16* __restrict__ WkB, u16* __restrict__ Kt, int b0, int NB)
{
  __shared__ u16 As[128 * 32], Bs[128 * 32];
  const int h = blockIdx.z;
  const int n0 = blockIdx.x * 128;    // o tile
  const int m0 = blockIdx.y * 128;    // token tile
  const u16* A = embA + (size_t)(b0 * 224 + m0) * 960;
  const u16* B = WkB + (size_t)h * 1024 * 960 + (size_t)n0 * 960;
  f32x4 acc[4][4] = {};
  mfma_core(A, 960, B, 960, 960, acc, As, Bs);
  const int tid = threadIdx.x, l = tid & 63, w = tid >> 6, wm = w >> 1, wn = w & 1;
  u16* C = Kt + (size_t)h * 1024 * NB;
#pragma unroll
  for (int i = 0; i < 4; ++i) {
    const int tok0 = m0 + wm * 64 + i * 16 + (l >> 4) * 4;
#pragma unroll
    for (int j = 0; j < 4; ++j) {
      const int o = n0 + wn * 64 + j * 16 + (l & 15);
      *(uint2*)(C + (size_t)o * NB + tok0) = pack4(acc[i][j]);
    }
  }
}

// V[lb*4+h][tok 256][o 1024]: A = WvB (M=o), B = embA (N=tok); r -> o (contig).
__global__ __launch_bounds__(256) void k_v(const u16* __restrict__ embA,
    const u16* __restrict__ WvB, u16* __restrict__ V, int b0, int NB)
{
  __shared__ u16 As[128 * 32], Bs[128 * 32];
  const int h = blockIdx.z;
  const int m0 = blockIdx.y * 128;    // o tile
  const int n0 = blockIdx.x * 128;    // token tile
  const u16* A = WvB + (size_t)h * 1024 * 960 + (size_t)m0 * 960;
  const u16* B = embA + (size_t)(b0 * 224 + n0) * 960;
  f32x4 acc[4][4] = {};
  mfma_core(A, 960, B, 960, 960, acc, As, Bs);
  const int tid = threadIdx.x, l = tid & 63, w = tid >> 6, wm = w >> 1, wn = w & 1;
#pragma unroll
  for (int i = 0; i < 4; ++i) {
    const int o0 = m0 + wm * 64 + i * 16 + (l >> 4) * 4;
#pragma unroll
    for (int j = 0; j < 4; ++j) {
      const int tok = n0 + wn * 64 + j * 16 + (l & 15);
      const int lb = tok / 224, nn = tok - lb * 224;
      *(uint2*)(V + ((size_t)(lb * 4 + h) * 256 + nn) * 1024 + o0) = pack4(acc[i][j]);
    }
  }
}

// Qt[h][ccat 1024][tok NB]: A = embA-slice (M=tok), B = WqB (N=c); r -> tok.
__global__ __launch_bounds__(256) void k_q(const u16* __restrict__ embA,
    const u16* __restrict__ WqB, u16* __restrict__ Qt, int b0, int NB)
{
  __shared__ u16 As[128 * 32], Bs[128 * 32];
  const int h = blockIdx.z;
  const int y = blockIdx.y;
  const int br = (y == 0) ? 0 : (y == 1) ? 1 : (y < 4) ? 2 : 3;
  const int mt = (y <= 1) ? 0 : (y < 4) ? (y - 2) : (y - 4);
  const int Ci = 64 << br;
  const int coff = (br == 0) ? 0 : (br == 1) ? 64 : (br == 2) ? 192 : 448;
  const int wqo = (br == 0) ? 0 : (br == 1) ? 8192 : (br == 2) ? 24576 : 90112;
  const int m0 = blockIdx.x * 128;    // token tile
  const u16* A = embA + (size_t)(b0 * 224 + m0) * 960 + coff;
  const u16* B = WqB + (size_t)h * 352256 + wqo + (size_t)mt * 128 * Ci;
  f32x4 acc[4][4] = {};
  mfma_core(A, 960, B, Ci, Ci, acc, As, Bs);
  const int tid = threadIdx.x, l = tid & 63, w = tid >> 6, wm = w >> 1, wn = w & 1;
  u16* C = Qt + (size_t)h * 1024 * NB;
#pragma unroll
  for (int i = 0; i < 4; ++i) {
    const int tok0 = m0 + wm * 64 + i * 16 + (l >> 4) * 4;
#pragma unroll
    for (int j = 0; j < 4; ++j) {
      const int lc = mt * 128 + wn * 64 + j * 16 + (l & 15);
      if (lc < Ci)
        *(uint2*)(C + (size_t)(coff + lc) * NB + tok0) = pack4(acc[i][j]);
    }
  }
}

// ---------------------------------------------------------------------------
// Gk[z][n' 224][n 224] = sum_o Kt[o,n']Kt[o,n]. Symmetric: store transposed.
// ---------------------------------------------------------------------------
#define TS_LD 72
__global__ __launch_bounds__(256) void k_gk(const u16* __restrict__ Kt,
                                            u16* __restrict__ Gk, int NB)
{
  __shared__ u16 TsA[128 * TS_LD], TsB[128 * TS_LD];
  const int z = blockIdx.z, lb = z >> 2, h = z & 3;
  const int n0a = blockIdx.y * 96, n0b = blockIdx.x * 96;
  const u16* Kz = Kt + (size_t)h * 1024 * NB + lb * 224;
  const int tid = threadIdx.x, l = tid & 63, w = tid >> 6, wm = w >> 1, wn = w & 1;
  f32x4 acc[4][4] = {};
  for (int o0 = 0; o0 < 1024; o0 += 64) {
    __syncthreads();
#pragma unroll
    for (int it = 0; it < 16; ++it) {
      const int e = it * 256 + tid;
      const int o = e >> 6, np = e & 63;
      const unsigned va = *(const unsigned*)(Kz + (size_t)(o0 + o) * NB + n0a + np * 2);
      const unsigned vb = *(const unsigned*)(Kz + (size_t)(o0 + o) * NB + n0b + np * 2);
      const int o8 = o >> 3, oe = o & 7;
      const int r0 = np * 2, r1 = r0 + 1;
      TsA[r0 * TS_LD + (((o8 ^ (r0 & 7)) << 3) | oe)] = (u16)(va & 0xffff);
      TsA[r1 * TS_LD + (((o8 ^ (r1 & 7)) << 3) | oe)] = (u16)(va >> 16);
      TsB[r0 * TS_LD + (((o8 ^ (r0 & 7)) << 3) | oe)] = (u16)(vb & 0xffff);
      TsB[r1 * TS_LD + (((o8 ^ (r1 & 7)) << 3) | oe)] = (u16)(vb >> 16);
    }
    __syncthreads();
#pragma unroll
    for (int ks = 0; ks < 2; ++ks) {
      bf16x8 av[4], bv[4];
#pragma unroll
      for (int i = 0; i < 4; ++i) {
        const int ra = wm * 64 + i * 16 + (l & 15);
        av[i] = *(const bf16x8*)(TsA + ra * TS_LD + (((ks * 4 + (l >> 4)) ^ (ra & 7)) << 3));
        const int rb = wn * 64 + i * 16 + (l & 15);
        bv[i] = *(const bf16x8*)(TsB + rb * TS_LD + (((ks * 4 + (l >> 4)) ^ (rb & 7)) << 3));
      }
#pragma unroll
      for (int i = 0; i < 4; ++i)
#pragma unroll
        for (int j = 0; j < 4; ++j)
          acc[i][j] = __builtin_amdgcn_mfma_f32_16x16x32_bf16(av[i], bv[j], acc[i][j], 0, 0, 0);
    }
  }
  u16* G = Gk + (size_t)z * 256 * 224;
#pragma unroll
  for (int i = 0; i < 4; ++i) {
    const int ra0 = n0a + wm * 64 + i * 16 + (l >> 4) * 4;
#pragma unroll
    for (int j = 0; j < 4; ++j) {
      const int cb = n0b + wn * 64 + j * 16 + (l & 15);
      *(uint2*)(G + (size_t)cb * 224 + ra0) = pack4(acc[i][j]);
    }
  }
}

// ---------------------------------------------------------------------------
// sumsq per (z, branch): Y^T = Gk x Qt^T, then dot with Q via vector loads.
// ---------------------------------------------------------------------------
__global__ __launch_bounds__(256) void k_qgq(const u16* __restrict__ Qt,
    const u16* __restrict__ Gk, float* __restrict__ stats, int NB)
{
  __shared__ u16 As[128 * 32], Bs[128 * 32];
  __shared__ float sb[4];
  const int z = blockIdx.z, lb = z >> 2, h = z & 3;
  const int m0 = blockIdx.y * 128;    // c tile
  const int tx = blockIdx.x;          // n' tile origin {0, 96}
  const int tid = threadIdx.x;
  if (tid < 4) sb[tid] = 0.f;
  const u16* A = Gk + (size_t)z * 256 * 224 + (size_t)(tx * 96) * 224;
  const u16* B = Qt + (size_t)h * 1024 * NB + (size_t)m0 * NB + lb * 224;
  f32x4 acc[4][4] = {};
  mfma_core(A, 224, B, NB, 224, acc, As, Bs);
  const int l = tid & 63, w = tid >> 6, wm = w >> 1, wn = w & 1;
  const u16* Qbase = Qt + (size_t)h * 1024 * NB + lb * 224;
  float part[4] = {};
  int pbr[4]; bool okj[4];
#pragma unroll
  for (int j = 0; j < 4; ++j) {
    const int cg = m0 + wn * 64 + j * 16 + (l & 15);
    pbr[j] = (cg < 64) ? 0 : (cg < 192) ? 1 : (cg < 448) ? 2 : 3;
    okj[j] = (cg < 960);
  }
#pragma unroll
  for (int i = 0; i < 4; ++i) {
    const int np0 = tx * 96 + wm * 64 + i * 16 + (l >> 4) * 4;
    if (tx == 1 && np0 < 128) continue;    // overlap region owned by tx=0
#pragma unroll
    for (int j = 0; j < 4; ++j) {
      if (!okj[j]) continue;
      const int cg = m0 + wn * 64 + j * 16 + (l & 15);
      const uint2 q = *(const uint2*)(Qbase + (size_t)cg * NB + np0);
      part[j] += acc[i][j][0] * bf2f((u16)(q.x & 0xffff))
               + acc[i][j][1] * bf2f((u16)(q.x >> 16))
               + acc[i][j][2] * bf2f((u16)(q.y & 0xffff))
               + acc[i][j][3] * bf2f((u16)(q.y >> 16));
    }
  }
  __syncthreads();
#pragma unroll
  for (int j = 0; j < 4; ++j)
    if (okj[j]) atomicAdd(&sb[pbr[j]], part[j]);
  __syncthreads();
  if (tid < 4) atomicAdd(stats + (size_t)z * 4 + tid, sb[tid]);
}

// ---------------------------------------------------------------------------
// Fused attention v6: identical schedule to v5 but __launch_bounds__(256,4):
// LDS 38.4KB x 4 = 153.6KB <= 160 -> 4 blocks/CU; grid 960 (Bc=16) fits in
// ONE residency round (1024 slots) instead of 2.
// ---------------------------------------------------------------------------
__global__ __launch_bounds__(256, 4) void k_att(
    const u16* __restrict__ Qt, const u16* __restrict__ Kt,
    const u16* __restrict__ V, const float* __restrict__ stats,
    u16* __restrict__ ctxh, int NB)
{
  __shared__ u16 smem[18944];     // 37888 B: K @0, V @7424, Ps @16384 (u16 idx)
  __shared__ float rsum[64];

  const int z = blockIdx.x, ct = blockIdx.y;
  const int lb = z >> 2, h = z & 3;
  const int c0 = ct * 64;
  const int tid = threadIdx.x, l = tid & 63, w = tid >> 6;
  const int wm = w >> 1, wn = w & 1;
  const int br = (c0 < 64) ? 0 : (c0 < 192) ? 1 : (c0 < 448) ? 2 : 3;
  const float scale = 0.03227486121839514f;   // 1/sqrt(960)
  const float cnt = (float)(64 << br) * 960.f;
  const float var = stats[(size_t)z * 4 + br] * scale * scale / cnt;
  const float cs = scale * rsqrtf(var + 1e-5f);

  const u16* Qz = Qt + (size_t)h * 1024 * NB + (size_t)c0 * NB + lb * 224;
  const u16* Kz = Kt + (size_t)h * 1024 * NB + lb * 224;
  const u16* Vz = V + (size_t)z * 256 * 1024;

  bf16x8 qa[2][7];
#pragma unroll
  for (int i = 0; i < 2; ++i)
#pragma unroll
    for (int ks = 0; ks < 7; ++ks)
      qa[i][ks] = *(const bf16x8*)(Qz + (size_t)(wm * 32 + i * 16 + (l & 15)) * NB
                                   + ks * 32 + (l >> 4) * 8);
  if (tid < 64) rsum[tid] = 0.f;

  const u16* kp[4];
#pragma unroll
  for (int s = 0; s < 4; ++s) {
    const int e16 = s * 256 + tid;
    const int row = e16 / 29, col = (e16 - row * 29) * 8;
    kp[s] = Kz + (size_t)row * NB + col;
  }
  const u16* vp[5];
#pragma unroll
  for (int s = 0; s < 5; ++s) {
    const int e16 = s * 256 + tid;
    const int row = e16 / 5, col = (e16 - row * 5) * 8;
    vp[s] = Vz + (size_t)row * 1024 + col;
  }
  u16* Ps = smem + 16384;
  const int wb = (tid & 192) * 16;

  f32x4 cacc[7][2] = {};
  float rp[2][4] = {};

  for (int oc = 0; oc < 30; ++oc) {
    __syncthreads();
#pragma unroll
    for (int s = 0; s < 3; ++s) { gload16(kp[s], (char*)smem + s * 4096 + wb); kp[s] += (size_t)32 * NB; }
    if (tid < 160)                { gload16(kp[3], (char*)smem + 12288 + wb); }
    kp[3] += (size_t)32 * NB;
#pragma unroll
    for (int s = 0; s < 4; ++s) { gload16(vp[s], (char*)smem + 14848 + s * 4096 + wb); vp[s] += 32; }
    if (tid < 96)               { gload16(vp[4], (char*)smem + 14848 + 16384 + wb); }
    vp[4] += 32;
    __syncthreads();
    f32x4 sacc[2] = {};
#pragma unroll
    for (int ks = 0; ks < 7; ++ks) {
      const bf16x8 kb = *(const bf16x8*)(smem + (wn * 16 + (l & 15)) * 232 + ks * 32 + (l >> 4) * 8);
#pragma unroll
      for (int i = 0; i < 2; ++i)
        sacc[i] = __builtin_amdgcn_mfma_f32_16x16x32_bf16(qa[i][ks], kb, sacc[i], 0, 0, 0);
    }
#pragma unroll
    for (int i = 0; i < 2; ++i)
#pragma unroll
      for (int r = 0; r < 4; ++r) {
        const float p = __expf(sacc[i][r] * cs);
        rp[i][r] += p;
        Ps[(wm * 32 + i * 16 + (l >> 4) * 4 + r) * 40 + wn * 16 + (l & 15)] = f2bf(p);
      }
    __syncthreads();
    bf16x8 pv[2];
#pragma unroll
    for (int j = 0; j < 2; ++j)
      pv[j] = *(const bf16x8*)(Ps + (wn * 32 + j * 16 + (l & 15)) * 40 + (l >> 4) * 8);
#pragma unroll
    for (int i2 = 0; i2 < 7; ++i2) {
      const bf16x8 av = *(const bf16x8*)(smem + 7424 + (wm * 112 + i2 * 16 + (l & 15)) * 40 + (l >> 4) * 8);
#pragma unroll
      for (int j = 0; j < 2; ++j)
        cacc[i2][j] = __builtin_amdgcn_mfma_f32_16x16x32_bf16(av, pv[j], cacc[i2][j], 0, 0, 0);
    }
  }
  __syncthreads();
#pragma unroll
  for (int i = 0; i < 2; ++i)
#pragma unroll
    for (int r = 0; r < 4; ++r) {
      float v = rp[i][r];
      v += __shfl_xor(v, 1); v += __shfl_xor(v, 2);
      v += __shfl_xor(v, 4); v += __shfl_xor(v, 8);
      if ((l & 15) == 0) atomicAdd(&rsum[wm * 32 + i * 16 + (l >> 4) * 4 + r], v);
    }
  __syncthreads();
  float inv[2];
#pragma unroll
  for (int j = 0; j < 2; ++j)
    inv[j] = 1.f / rsum[wn * 32 + j * 16 + (l & 15)];

  u16* Cs = smem;
  u16* dst = ctxh + (size_t)z * 229376 + c0;
#pragma unroll
  for (int pass = 0; pass < 2; ++pass) {
    __syncthreads();
    if (wm == pass) {
#pragma unroll
      for (int i2 = 0; i2 < 7; ++i2)
#pragma unroll
        for (int j = 0; j < 2; ++j)
#pragma unroll
          for (int r = 0; r < 4; ++r)
            Cs[(i2 * 16 + (l >> 4) * 4 + r) * 72 + wn * 32 + j * 16 + (l & 15)]
                = f2bf(cacc[i2][j][r] * inv[j]);
    }
    __syncthreads();
    for (int u = tid; u < 112 * 8; u += 256) {
      const int row = u >> 3, c8 = u & 7;
      *(uint4*)(dst + (size_t)(pass * 112 + row) * 1024 + c8 * 8) =
          *(const uint4*)(Cs + row * 72 + c8 * 8);
    }
  }
}

// ---------------------------------------------------------------------------
// O_br[b][n][c'] with fused head-average: B tile = 0.25 * sum_h ctxh[z][n][c],
// reg-staged (4x bf16x8 load + f32 sum -> LDS). A = WoB (M=c'); r -> c'
// contiguous -> f32x4 store. Replaces k_ctxred + old k_o.
// ---------------------------------------------------------------------------
__global__ __launch_bounds__(256) void k_o(const u16* __restrict__ ctxh,
    const u16* __restrict__ WoB, float* __restrict__ out, int b0)
{
  __shared__ u16 As[128 * 32], Bs[128 * 32];
  const int lb = blockIdx.z;
  const int x = blockIdx.x;
  const int br = (x == 0) ? 0 : (x == 1) ? 1 : (x < 4) ? 2 : 3;
  const int mt = (x <= 1) ? 0 : (x < 4) ? (x - 2) : (x - 4);
  const int Ci = 64 << br;
  const int coff = (br == 0) ? 0 : (br == 1) ? 64 : (br == 2) ? 192 : 448;
  const int woo = (br == 0) ? 0 : (br == 1) ? 8192 : (br == 2) ? 24576 : 90112;
  const long long ob = (br == 0) ? 0LL : (br == 1) ? 401408LL : (br == 2) ? 1204224LL : 2809856LL;
  const int n0 = blockIdx.y * 128;    // token tile
  const u16* A = WoB + woo + (size_t)mt * 128 * Ci;
  const u16* Bz = ctxh + (size_t)lb * 4 * 229376 + coff;
  const int tid = threadIdx.x, l = tid & 63, w = tid >> 6, wm = w >> 1, wn = w & 1;
  // A staging pointers (mfma_core pattern)
  const int srow = w * 16 + (l >> 2);
  const int kel  = (l & 3) * 8;
  char* AsB = (char*)As + w * 1024;
  const u16* Ap  = A + (size_t)srow * Ci + kel;
  const u16* Ap2 = A + (size_t)(srow + 64) * Ci + kel;
  const int aoff = (wm * 64 + (l & 15)) * 32 + (l >> 4) * 8;
  const int boff = (wn * 64 + (l & 15)) * 32 + (l >> 4) * 8;
  // B slot (2 per thread): slot = s*256+tid; row = slot>>2, kq = slot&3
  f32x4 acc[4][4] = {};
  for (int kb = 0; kb < Ci; kb += 32) {
    __syncthreads();
    gload16(Ap + kb,  AsB);
    gload16(Ap2 + kb, AsB + 4096);
#pragma unroll
    for (int s = 0; s < 2; ++s) {
      const int slot = s * 256 + tid;
      const int row = slot >> 2, kq = slot & 3;
      const int tok = n0 + row;
      float sum[8] = {};
      if (tok < 224) {
        const u16* p = Bz + (size_t)tok * 1024 + kb + kq * 8;
#pragma unroll
        for (int hh = 0; hh < 4; ++hh) {
          const bf16x8 v = *(const bf16x8*)(p + (size_t)hh * 229376);
#pragma unroll
          for (int e = 0; e < 8; ++e) sum[e] += bf2f((u16)v[e]);
        }
      }
      bf16x8 o;
#pragma unroll
      for (int e = 0; e < 8; ++e) o[e] = (short)f2bf(sum[e] * 0.25f);
      *(bf16x8*)(Bs + row * 32 + kq * 8) = o;
    }
    __syncthreads();
    bf16x8 av[4], bv[4];
#pragma unroll
    for (int i = 0; i < 4; ++i) {
      av[i] = *(const bf16x8*)(As + aoff + i * 16 * 32);
      bv[i] = *(const bf16x8*)(Bs + boff + i * 16 * 32);
    }
#pragma unroll
    for (int i = 0; i < 4; ++i)
#pragma unroll
      for (int j = 0; j < 4; ++j)
        acc[i][j] = __builtin_amdgcn_mfma_f32_16x16x32_bf16(av[i], bv[j], acc[i][j], 0, 0, 0);
  }
  float* O = out + ob;
  const int gb = b0 + lb;
#pragma unroll
  for (int i = 0; i < 4; ++i) {
    const int cp0 = mt * 128 + wm * 64 + i * 16 + (l >> 4) * 4;
    if (cp0 >= Ci) continue;
#pragma unroll
    for (int j = 0; j < 4; ++j) {
      const int n = n0 + wn * 64 + j * 16 + (l & 15);
      if (n < 196)
        *(f32x4*)(O + ((size_t)gb * 196 + n) * Ci + cp0) = acc[i][j];
    }
  }
}

// ---------------------------------------------------------------------------
extern "C" void kernel_launch(void* const* d_in, const int* in_sizes, int n_in,
                              void* d_out, int out_size, void* d_ws, size_t ws_size,
                              hipStream_t stream)
{
  const float* eall = (const float*)d_in[4];
  const float* Wq1 = (const float*)d_in[5];
  const float* Wq2 = (const float*)d_in[6];
  const float* Wq3 = (const float*)d_in[7];
  const float* Wq4 = (const float*)d_in[8];
  const float* Wk  = (const float*)d_in[9];
  const float* Wv  = (const float*)d_in[10];
  const float* Wo1 = (const float*)d_in[11];
  const float* Wo2 = (const float*)d_in[12];
  const float* Wo3 = (const float*)d_in[13];
  const float* Wo4 = (const float*)d_in[14];
  float* out = (float*)d_out;

  char* p = (char*)d_ws;
  auto alloc = [&](size_t bytes) -> void* {
    void* r = p; p += (bytes + 255) & ~(size_t)255; return r;
  };
  u16* embA = (u16*)alloc((size_t)7168 * 960 * 2);
  u16* WkB  = (u16*)alloc((size_t)4 * 1024 * 960 * 2);
  u16* WvB  = (u16*)alloc((size_t)4 * 1024 * 960 * 2);
  u16* WqB  = (u16*)alloc((size_t)4 * 352256 * 2);
  u16* WoB  = (u16*)alloc((size_t)352256 * 2);
  const size_t persist = (size_t)(p - (char*)d_ws);
  // per-lb: Kt+Qt 3.67M + V 2.10M + Gk 0.46M + ctxh 1.84M (+ stats)
  const size_t perLB = (size_t)1835008 * 2 + 2097152 + 458752 + 1835008 + 64 + 2048;
  int Bc = 8;
  if      (persist + 32 * perLB <= ws_size) Bc = 32;
  else if (persist + 16 * perLB <= ws_size) Bc = 16;
  const int NB = Bc * 224;
  const int Z = Bc * 4;

  u16* Kt  = (u16*)alloc((size_t)4 * 1024 * NB * 2);
  u16* Qt  = (u16*)alloc((size_t)4 * 1024 * NB * 2);
  u16* V   = (u16*)alloc((size_t)Bc * 4 * 256 * 1024 * 2);
  u16* Gk  = (u16*)alloc((size_t)Bc * 4 * 256 * 224 * 2);
  u16* ctxh = (u16*)alloc((size_t)Bc * 4 * 229376 * 2);
  float* stats = (float*)alloc((size_t)Bc * 16 * 4);

  const dim3 blk(256);
  k_cvt<<<dim3(64480), blk, 0, stream>>>(eall, Wq1, Wq2, Wq3, Wq4, Wk, Wv,
                                         Wo1, Wo2, Wo3, Wo4,
                                         embA, WkB, WvB, WqB, WoB);

  const int NT = NB / 128;
  for (int b0 = 0; b0 < 32; b0 += Bc) {
    (void)hipMemsetAsync(stats, 0, (size_t)Bc * 16 * 4, stream);
    k_kt<<<dim3(8, NT, 4), blk, 0, stream>>>(embA, WkB, Kt, b0, NB);
    k_v <<<dim3(NT, 8, 4), blk, 0, stream>>>(embA, WvB, V, b0, NB);
    k_q <<<dim3(NT, 8, 4), blk, 0, stream>>>(embA, WqB, Qt, b0, NB);
    k_gk<<<dim3(2, 2, Z), blk, 0, stream>>>(Kt, Gk, NB);
    k_qgq<<<dim3(2, 8, Z), blk, 0, stream>>>(Qt, Gk, stats, NB);
    k_att<<<dim3(Z, 15), blk, 0, stream>>>(Qt, Kt, V, stats, ctxh, NB);
    k_o <<<dim3(8, 2, Bc), blk, 0, stream>>>(ctxh, WoB, out, b0);
  }
}

// Round 14
// 857.417 us; speedup vs baseline: 1.2604x; 1.2604x over previous
//
#include <hip/hip_runtime.h>
#include <math.h>

typedef __attribute__((ext_vector_type(8))) short bf16x8;   // 8 bf16 in 4 VGPRs
typedef __attribute__((ext_vector_type(4))) float f32x4;
typedef unsigned short u16;

__device__ __forceinline__ u16 f2bf(float f) {
  unsigned u = __float_as_uint(f);
  return (u16)((u + 0x7FFFu + ((u >> 16) & 1u)) >> 16);   // RNE
}
__device__ __forceinline__ float bf2f(u16 h) {
  return __uint_as_float(((unsigned)h) << 16);
}
__device__ __forceinline__ uint2 pack4(const f32x4 v) {
  uint2 r;
  r.x = (unsigned)f2bf(v[0]) | ((unsigned)f2bf(v[1]) << 16);
  r.y = (unsigned)f2bf(v[2]) | ((unsigned)f2bf(v[3]) << 16);
  return r;
}

__device__ __forceinline__ void gload16(const u16* g, void* lds) {
  __builtin_amdgcn_global_load_lds(
      (const __attribute__((address_space(1))) unsigned int*)g,
      (__attribute__((address_space(3))) unsigned int*)lds, 16, 0, 0);
}

// ---------------------------------------------------------------------------
// MFMA core (proven): 128x128 tile, BK=32, 256 threads (4 waves = 2x2
// quadrants of 4x4 16x16x32 fragments). K mult of 32; padded buffers.
// acc[i][j] fragment: row (M) = wm*64+i*16+(l>>4)*4+r, col (N) = wn*64+j*16+(l&15)
// ---------------------------------------------------------------------------
__device__ __forceinline__ void mfma_core(
    const u16* __restrict__ A, int lda,
    const u16* __restrict__ B, int ldb,
    int K, f32x4 (&acc)[4][4], u16* As, u16* Bs)
{
  const int tid = threadIdx.x;
  const int l = tid & 63, w = tid >> 6;
  const int srow = w * 16 + (l >> 2);
  const int kel  = (l & 3) * 8;
  char* AsB = (char*)As + w * 1024;
  char* BsB = (char*)Bs + w * 1024;
  const u16* Ap  = A + (size_t)srow * lda + kel;
  const u16* Ap2 = A + (size_t)(srow + 64) * lda + kel;
  const u16* Bp  = B + (size_t)srow * ldb + kel;
  const u16* Bp2 = B + (size_t)(srow + 64) * ldb + kel;
  const int wm = w >> 1, wn = w & 1;
  const int aoff = (wm * 64 + (l & 15)) * 32 + (l >> 4) * 8;
  const int boff = (wn * 64 + (l & 15)) * 32 + (l >> 4) * 8;
  for (int kb = 0; kb < K; kb += 32) {
    __syncthreads();
    gload16(Ap + kb,  AsB);
    gload16(Ap2 + kb, AsB + 4096);
    gload16(Bp + kb,  BsB);
    gload16(Bp2 + kb, BsB + 4096);
    __syncthreads();
    bf16x8 av[4], bv[4];
#pragma unroll
    for (int i = 0; i < 4; ++i) {
      av[i] = *(const bf16x8*)(As + aoff + i * 16 * 32);
      bv[i] = *(const bf16x8*)(Bs + boff + i * 16 * 32);
    }
#pragma unroll
    for (int i = 0; i < 4; ++i)
#pragma unroll
      for (int j = 0; j < 4; ++j)
        acc[i][j] = __builtin_amdgcn_mfma_f32_16x16x32_bf16(av[i], bv[j], acc[i][j], 0, 0, 0);
  }
}

// ---------------------------------------------------------------------------
// One-shot pad/convert of all inputs (11 segments, hardcoded boundaries).
// ---------------------------------------------------------------------------
__global__ __launch_bounds__(256) void k_cvt(
    const float* __restrict__ eall,
    const float* __restrict__ Wq1, const float* __restrict__ Wq2,
    const float* __restrict__ Wq3, const float* __restrict__ Wq4,
    const float* __restrict__ Wk, const float* __restrict__ Wv,
    const float* __restrict__ Wo1, const float* __restrict__ Wo2,
    const float* __restrict__ Wo3, const float* __restrict__ Wo4,
    u16* __restrict__ embA, u16* __restrict__ WkB, u16* __restrict__ WvB,
    u16* __restrict__ WqB, u16* __restrict__ WoB)
{
  long long idx = (long long)blockIdx.x * 256 + threadIdx.x;
  const float* src; u16* dst; int srcR, dstR, C; long long stride, off, loc;
  if (idx < 6881280LL)       { loc = idx;               src=eall; dst=embA; srcR=196; dstR=224;  C=960; stride=215040; off=0; }
  else if (idx < 10813440LL) { loc = idx - 6881280LL;   src=Wk;   dst=WkB;  srcR=960; dstR=1024; C=960; stride=983040; off=0; }
  else if (idx < 14745600LL) { loc = idx - 10813440LL;  src=Wv;   dst=WvB;  srcR=960; dstR=1024; C=960; stride=983040; off=0; }
  else if (idx < 14778368LL) { loc = idx - 14745600LL;  src=Wq1;  dst=WqB;  srcR=64;  dstR=128;  C=64;  stride=352256; off=0; }
  else if (idx < 14843904LL) { loc = idx - 14778368LL;  src=Wq2;  dst=WqB;  srcR=128; dstR=128;  C=128; stride=352256; off=8192; }
  else if (idx < 15106048LL) { loc = idx - 14843904LL;  src=Wq3;  dst=WqB;  srcR=256; dstR=256;  C=256; stride=352256; off=24576; }
  else if (idx < 16154624LL) { loc = idx - 15106048LL;  src=Wq4;  dst=WqB;  srcR=512; dstR=512;  C=512; stride=352256; off=90112; }
  else if (idx < 16162816LL) { loc = idx - 16154624LL;  src=Wo1;  dst=WoB;  srcR=64;  dstR=128;  C=64;  stride=0; off=0; }
  else if (idx < 16179200LL) { loc = idx - 16162816LL;  src=Wo2;  dst=WoB;  srcR=128; dstR=128;  C=128; stride=0; off=8192; }
  else if (idx < 16244736LL) { loc = idx - 16179200LL;  src=Wo3;  dst=WoB;  srcR=256; dstR=256;  C=256; stride=0; off=24576; }
  else if (idx < 16506880LL) { loc = idx - 16244736LL;  src=Wo4;  dst=WoB;  srcR=512; dstR=512;  C=512; stride=0; off=90112; }
  else return;
  const long long per = (long long)dstR * C;
  const int g = (int)(loc / per);
  const int r2 = (int)(loc % per);
  const int rr = r2 / C, c = r2 - rr * C;
  const float v = (rr < srcR) ? src[((long long)g * srcR + rr) * C + c] : 0.f;
  dst[g * stride + off + (long long)rr * C + c] = f2bf(v);
}

// Kt[h][o 1024][tok NB]: A = embA (M=tok), B = WkB (N=o); r -> tok (contig).
__global__ __launch_bounds__(256) void k_kt(const u16* __restrict__ embA,
    const u16* __restrict__ WkB, u16* __restrict__ Kt, int b0, int NB)
{
  __shared__ u16 As[128 * 32], Bs[128 * 32];
  const int h = blockIdx.z;
  const int n0 = blockIdx.x * 128;    // o tile
  const int m0 = blockIdx.y * 128;    // token tile
  const u16* A = embA + (size_t)(b0 * 224 + m0) * 960;
  const u16* B = WkB + (size_t)h * 1024 * 960 + (size_t)n0 * 960;
  f32x4 acc[4][4] = {};
  mfma_core(A, 960, B, 960, 960, acc, As, Bs);
  const int tid = threadIdx.x, l = tid & 63, w = tid >> 6, wm = w >> 1, wn = w & 1;
  u16* C = Kt + (size_t)h * 1024 * NB;
#pragma unroll
  for (int i = 0; i < 4; ++i) {
    const int tok0 = m0 + wm * 64 + i * 16 + (l >> 4) * 4;
#pragma unroll
    for (int j = 0; j < 4; ++j) {
      const int o = n0 + wn * 64 + j * 16 + (l & 15);
      *(uint2*)(C + (size_t)o * NB + tok0) = pack4(acc[i][j]);
    }
  }
}

// V[lb*4+h][tok 256][o 1024]: A = WvB (M=o), B = embA (N=tok); r -> o (contig).
__global__ __launch_bounds__(256) void k_v(const u16* __restrict__ embA,
    const u16* __restrict__ WvB, u16* __restrict__ V, int b0, int NB)
{
  __shared__ u16 As[128 * 32], Bs[128 * 32];
  const int h = blockIdx.z;
  const int m0 = blockIdx.y * 128;    // o tile
  const int n0 = blockIdx.x * 128;    // token tile
  const u16* A = WvB + (size_t)h * 1024 * 960 + (size_t)m0 * 960;
  const u16* B = embA + (size_t)(b0 * 224 + n0) * 960;
  f32x4 acc[4][4] = {};
  mfma_core(A, 960, B, 960, 960, acc, As, Bs);
  const int tid = threadIdx.x, l = tid & 63, w = tid >> 6, wm = w >> 1, wn = w & 1;
#pragma unroll
  for (int i = 0; i < 4; ++i) {
    const int o0 = m0 + wm * 64 + i * 16 + (l >> 4) * 4;
#pragma unroll
    for (int j = 0; j < 4; ++j) {
      const int tok = n0 + wn * 64 + j * 16 + (l & 15);
      const int lb = tok / 224, nn = tok - lb * 224;
      *(uint2*)(V + ((size_t)(lb * 4 + h) * 256 + nn) * 1024 + o0) = pack4(acc[i][j]);
    }
  }
}

// Qt[h][ccat 1024][tok NB]: A = embA-slice (M=tok), B = WqB (N=c); r -> tok.
__global__ __launch_bounds__(256) void k_q(const u16* __restrict__ embA,
    const u16* __restrict__ WqB, u16* __restrict__ Qt, int b0, int NB)
{
  __shared__ u16 As[128 * 32], Bs[128 * 32];
  const int h = blockIdx.z;
  const int y = blockIdx.y;
  const int br = (y == 0) ? 0 : (y == 1) ? 1 : (y < 4) ? 2 : 3;
  const int mt = (y <= 1) ? 0 : (y < 4) ? (y - 2) : (y - 4);
  const int Ci = 64 << br;
  const int coff = (br == 0) ? 0 : (br == 1) ? 64 : (br == 2) ? 192 : 448;
  const int wqo = (br == 0) ? 0 : (br == 1) ? 8192 : (br == 2) ? 24576 : 90112;
  const int m0 = blockIdx.x * 128;    // token tile
  const u16* A = embA + (size_t)(b0 * 224 + m0) * 960 + coff;
  const u16* B = WqB + (size_t)h * 352256 + wqo + (size_t)mt * 128 * Ci;
  f32x4 acc[4][4] = {};
  mfma_core(A, 960, B, Ci, Ci, acc, As, Bs);
  const int tid = threadIdx.x, l = tid & 63, w = tid >> 6, wm = w >> 1, wn = w & 1;
  u16* C = Qt + (size_t)h * 1024 * NB;
#pragma unroll
  for (int i = 0; i < 4; ++i) {
    const int tok0 = m0 + wm * 64 + i * 16 + (l >> 4) * 4;
#pragma unroll
    for (int j = 0; j < 4; ++j) {
      const int lc = mt * 128 + wn * 64 + j * 16 + (l & 15);
      if (lc < Ci)
        *(uint2*)(C + (size_t)(coff + lc) * NB + tok0) = pack4(acc[i][j]);
    }
  }
}

// ---------------------------------------------------------------------------
// Gk[z][n' 224][n 224] = sum_o Kt[o,n']Kt[o,n]. Symmetric: store transposed.
// ---------------------------------------------------------------------------
#define TS_LD 72
__global__ __launch_bounds__(256) void k_gk(const u16* __restrict__ Kt,
                                            u16* __restrict__ Gk, int NB)
{
  __shared__ u16 TsA[128 * TS_LD], TsB[128 * TS_LD];
  const int z = blockIdx.z, lb = z >> 2, h = z & 3;
  const int n0a = blockIdx.y * 96, n0b = blockIdx.x * 96;
  const u16* Kz = Kt + (size_t)h * 1024 * NB + lb * 224;
  const int tid = threadIdx.x, l = tid & 63, w = tid >> 6, wm = w >> 1, wn = w & 1;
  f32x4 acc[4][4] = {};
  for (int o0 = 0; o0 < 1024; o0 += 64) {
    __syncthreads();
#pragma unroll
    for (int it = 0; it < 16; ++it) {
      const int e = it * 256 + tid;
      const int o = e >> 6, np = e & 63;
      const unsigned va = *(const unsigned*)(Kz + (size_t)(o0 + o) * NB + n0a + np * 2);
      const unsigned vb = *(const unsigned*)(Kz + (size_t)(o0 + o) * NB + n0b + np * 2);
      const int o8 = o >> 3, oe = o & 7;
      const int r0 = np * 2, r1 = r0 + 1;
      TsA[r0 * TS_LD + (((o8 ^ (r0 & 7)) << 3) | oe)] = (u16)(va & 0xffff);
      TsA[r1 * TS_LD + (((o8 ^ (r1 & 7)) << 3) | oe)] = (u16)(va >> 16);
      TsB[r0 * TS_LD + (((o8 ^ (r0 & 7)) << 3) | oe)] = (u16)(vb & 0xffff);
      TsB[r1 * TS_LD + (((o8 ^ (r1 & 7)) << 3) | oe)] = (u16)(vb >> 16);
    }
    __syncthreads();
#pragma unroll
    for (int ks = 0; ks < 2; ++ks) {
      bf16x8 av[4], bv[4];
#pragma unroll
      for (int i = 0; i < 4; ++i) {
        const int ra = wm * 64 + i * 16 + (l & 15);
        av[i] = *(const bf16x8*)(TsA + ra * TS_LD + (((ks * 4 + (l >> 4)) ^ (ra & 7)) << 3));
        const int rb = wn * 64 + i * 16 + (l & 15);
        bv[i] = *(const bf16x8*)(TsB + rb * TS_LD + (((ks * 4 + (l >> 4)) ^ (rb & 7)) << 3));
      }
#pragma unroll
      for (int i = 0; i < 4; ++i)
#pragma unroll
        for (int j = 0; j < 4; ++j)
          acc[i][j] = __builtin_amdgcn_mfma_f32_16x16x32_bf16(av[i], bv[j], acc[i][j], 0, 0, 0);
    }
  }
  u16* G = Gk + (size_t)z * 256 * 224;
#pragma unroll
  for (int i = 0; i < 4; ++i) {
    const int ra0 = n0a + wm * 64 + i * 16 + (l >> 4) * 4;
#pragma unroll
    for (int j = 0; j < 4; ++j) {
      const int cb = n0b + wn * 64 + j * 16 + (l & 15);
      *(uint2*)(G + (size_t)cb * 224 + ra0) = pack4(acc[i][j]);
    }
  }
}

// ---------------------------------------------------------------------------
// sumsq per (z, branch): Y^T = Gk x Qt^T, then dot with Q via vector loads.
// ---------------------------------------------------------------------------
__global__ __launch_bounds__(256) void k_qgq(const u16* __restrict__ Qt,
    const u16* __restrict__ Gk, float* __restrict__ stats, int NB)
{
  __shared__ u16 As[128 * 32], Bs[128 * 32];
  __shared__ float sb[4];
  const int z = blockIdx.z, lb = z >> 2, h = z & 3;
  const int m0 = blockIdx.y * 128;    // c tile
  const int tx = blockIdx.x;          // n' tile origin {0, 96}
  const int tid = threadIdx.x;
  if (tid < 4) sb[tid] = 0.f;
  const u16* A = Gk + (size_t)z * 256 * 224 + (size_t)(tx * 96) * 224;
  const u16* B = Qt + (size_t)h * 1024 * NB + (size_t)m0 * NB + lb * 224;
  f32x4 acc[4][4] = {};
  mfma_core(A, 224, B, NB, 224, acc, As, Bs);
  const int l = tid & 63, w = tid >> 6, wm = w >> 1, wn = w & 1;
  const u16* Qbase = Qt + (size_t)h * 1024 * NB + lb * 224;
  float part[4] = {};
  int pbr[4]; bool okj[4];
#pragma unroll
  for (int j = 0; j < 4; ++j) {
    const int cg = m0 + wn * 64 + j * 16 + (l & 15);
    pbr[j] = (cg < 64) ? 0 : (cg < 192) ? 1 : (cg < 448) ? 2 : 3;
    okj[j] = (cg < 960);
  }
#pragma unroll
  for (int i = 0; i < 4; ++i) {
    const int np0 = tx * 96 + wm * 64 + i * 16 + (l >> 4) * 4;
    if (tx == 1 && np0 < 128) continue;    // overlap region owned by tx=0
#pragma unroll
    for (int j = 0; j < 4; ++j) {
      if (!okj[j]) continue;
      const int cg = m0 + wn * 64 + j * 16 + (l & 15);
      const uint2 q = *(const uint2*)(Qbase + (size_t)cg * NB + np0);
      part[j] += acc[i][j][0] * bf2f((u16)(q.x & 0xffff))
               + acc[i][j][1] * bf2f((u16)(q.x >> 16))
               + acc[i][j][2] * bf2f((u16)(q.y & 0xffff))
               + acc[i][j][3] * bf2f((u16)(q.y >> 16));
    }
  }
  __syncthreads();
#pragma unroll
  for (int j = 0; j < 4; ++j)
    if (okj[j]) atomicAdd(&sb[pbr[j]], part[j]);
  __syncthreads();
  if (tid < 4) atomicAdd(stats + (size_t)z * 4 + tid, sb[tid]);
}

// ---------------------------------------------------------------------------
// Fused attention v5 (R11 schedule, launch_bounds(256,3) -- VGPR 84, NO spill;
// R13's (256,4) forced 64-VGPR budget -> scratch spill -> 7x FETCH, 2x time).
// ---------------------------------------------------------------------------
__global__ __launch_bounds__(256, 3) void k_att(
    const u16* __restrict__ Qt, const u16* __restrict__ Kt,
    const u16* __restrict__ V, const float* __restrict__ stats,
    u16* __restrict__ ctxh, int NB)
{
  __shared__ u16 smem[18944];     // 37888 B: K @0, V @7424, Ps @16384 (u16 idx)
  __shared__ float rsum[64];

  const int z = blockIdx.x, ct = blockIdx.y;
  const int lb = z >> 2, h = z & 3;
  const int c0 = ct * 64;
  const int tid = threadIdx.x, l = tid & 63, w = tid >> 6;
  const int wm = w >> 1, wn = w & 1;
  const int br = (c0 < 64) ? 0 : (c0 < 192) ? 1 : (c0 < 448) ? 2 : 3;
  const float scale = 0.03227486121839514f;   // 1/sqrt(960)
  const float cnt = (float)(64 << br) * 960.f;
  const float var = stats[(size_t)z * 4 + br] * scale * scale / cnt;
  const float cs = scale * rsqrtf(var + 1e-5f);

  const u16* Qz = Qt + (size_t)h * 1024 * NB + (size_t)c0 * NB + lb * 224;
  const u16* Kz = Kt + (size_t)h * 1024 * NB + lb * 224;
  const u16* Vz = V + (size_t)z * 256 * 1024;

  bf16x8 qa[2][7];
#pragma unroll
  for (int i = 0; i < 2; ++i)
#pragma unroll
    for (int ks = 0; ks < 7; ++ks)
      qa[i][ks] = *(const bf16x8*)(Qz + (size_t)(wm * 32 + i * 16 + (l & 15)) * NB
                                   + ks * 32 + (l >> 4) * 8);
  if (tid < 64) rsum[tid] = 0.f;

  const u16* kp[4];
#pragma unroll
  for (int s = 0; s < 4; ++s) {
    const int e16 = s * 256 + tid;
    const int row = e16 / 29, col = (e16 - row * 29) * 8;
    kp[s] = Kz + (size_t)row * NB + col;
  }
  const u16* vp[5];
#pragma unroll
  for (int s = 0; s < 5; ++s) {
    const int e16 = s * 256 + tid;
    const int row = e16 / 5, col = (e16 - row * 5) * 8;
    vp[s] = Vz + (size_t)row * 1024 + col;
  }
  u16* Ps = smem + 16384;
  const int wb = (tid & 192) * 16;

  f32x4 cacc[7][2] = {};
  float rp[2][4] = {};

  for (int oc = 0; oc < 30; ++oc) {
    __syncthreads();
#pragma unroll
    for (int s = 0; s < 3; ++s) { gload16(kp[s], (char*)smem + s * 4096 + wb); kp[s] += (size_t)32 * NB; }
    if (tid < 160)                { gload16(kp[3], (char*)smem + 12288 + wb); }
    kp[3] += (size_t)32 * NB;
#pragma unroll
    for (int s = 0; s < 4; ++s) { gload16(vp[s], (char*)smem + 14848 + s * 4096 + wb); vp[s] += 32; }
    if (tid < 96)               { gload16(vp[4], (char*)smem + 14848 + 16384 + wb); }
    vp[4] += 32;
    __syncthreads();
    f32x4 sacc[2] = {};
#pragma unroll
    for (int ks = 0; ks < 7; ++ks) {
      const bf16x8 kb = *(const bf16x8*)(smem + (wn * 16 + (l & 15)) * 232 + ks * 32 + (l >> 4) * 8);
#pragma unroll
      for (int i = 0; i < 2; ++i)
        sacc[i] = __builtin_amdgcn_mfma_f32_16x16x32_bf16(qa[i][ks], kb, sacc[i], 0, 0, 0);
    }
#pragma unroll
    for (int i = 0; i < 2; ++i)
#pragma unroll
      for (int r = 0; r < 4; ++r) {
        const float p = __expf(sacc[i][r] * cs);
        rp[i][r] += p;
        Ps[(wm * 32 + i * 16 + (l >> 4) * 4 + r) * 40 + wn * 16 + (l & 15)] = f2bf(p);
      }
    __syncthreads();
    bf16x8 pv[2];
#pragma unroll
    for (int j = 0; j < 2; ++j)
      pv[j] = *(const bf16x8*)(Ps + (wn * 32 + j * 16 + (l & 15)) * 40 + (l >> 4) * 8);
#pragma unroll
    for (int i2 = 0; i2 < 7; ++i2) {
      const bf16x8 av = *(const bf16x8*)(smem + 7424 + (wm * 112 + i2 * 16 + (l & 15)) * 40 + (l >> 4) * 8);
#pragma unroll
      for (int j = 0; j < 2; ++j)
        cacc[i2][j] = __builtin_amdgcn_mfma_f32_16x16x32_bf16(av, pv[j], cacc[i2][j], 0, 0, 0);
    }
  }
  __syncthreads();
#pragma unroll
  for (int i = 0; i < 2; ++i)
#pragma unroll
    for (int r = 0; r < 4; ++r) {
      float v = rp[i][r];
      v += __shfl_xor(v, 1); v += __shfl_xor(v, 2);
      v += __shfl_xor(v, 4); v += __shfl_xor(v, 8);
      if ((l & 15) == 0) atomicAdd(&rsum[wm * 32 + i * 16 + (l >> 4) * 4 + r], v);
    }
  __syncthreads();
  float inv[2];
#pragma unroll
  for (int j = 0; j < 2; ++j)
    inv[j] = 1.f / rsum[wn * 32 + j * 16 + (l & 15)];

  u16* Cs = smem;
  u16* dst = ctxh + (size_t)z * 229376 + c0;
#pragma unroll
  for (int pass = 0; pass < 2; ++pass) {
    __syncthreads();
    if (wm == pass) {
#pragma unroll
      for (int i2 = 0; i2 < 7; ++i2)
#pragma unroll
        for (int j = 0; j < 2; ++j)
#pragma unroll
          for (int r = 0; r < 4; ++r)
            Cs[(i2 * 16 + (l >> 4) * 4 + r) * 72 + wn * 32 + j * 16 + (l & 15)]
                = f2bf(cacc[i2][j][r] * inv[j]);
    }
    __syncthreads();
    for (int u = tid; u < 112 * 8; u += 256) {
      const int row = u >> 3, c8 = u & 7;
      *(uint4*)(dst + (size_t)(pass * 112 + row) * 1024 + c8 * 8) =
          *(const uint4*)(Cs + row * 72 + c8 * 8);
    }
  }
}

// ---------------------------------------------------------------------------
// O_br[b][n][c'] with fused head-average: B tile = 0.25 * sum_h ctxh[z][n][c],
// reg-staged (4x bf16x8 load + f32 sum -> LDS). A = WoB (M=c'); r -> c'
// contiguous -> f32x4 store. Replaces k_ctxred + old k_o.
// ---------------------------------------------------------------------------
__global__ __launch_bounds__(256) void k_o(const u16* __restrict__ ctxh,
    const u16* __restrict__ WoB, float* __restrict__ out, int b0)
{
  __shared__ u16 As[128 * 32], Bs[128 * 32];
  const int lb = blockIdx.z;
  const int x = blockIdx.x;
  const int br = (x == 0) ? 0 : (x == 1) ? 1 : (x < 4) ? 2 : 3;
  const int mt = (x <= 1) ? 0 : (x < 4) ? (x - 2) : (x - 4);
  const int Ci = 64 << br;
  const int coff = (br == 0) ? 0 : (br == 1) ? 64 : (br == 2) ? 192 : 448;
  const int woo = (br == 0) ? 0 : (br == 1) ? 8192 : (br == 2) ? 24576 : 90112;
  const long long ob = (br == 0) ? 0LL : (br == 1) ? 401408LL : (br == 2) ? 1204224LL : 2809856LL;
  const int n0 = blockIdx.y * 128;    // token tile
  const u16* A = WoB + woo + (size_t)mt * 128 * Ci;
  const u16* Bz = ctxh + (size_t)lb * 4 * 229376 + coff;
  const int tid = threadIdx.x, l = tid & 63, w = tid >> 6, wm = w >> 1, wn = w & 1;
  const int srow = w * 16 + (l >> 2);
  const int kel  = (l & 3) * 8;
  char* AsB = (char*)As + w * 1024;
  const u16* Ap  = A + (size_t)srow * Ci + kel;
  const u16* Ap2 = A + (size_t)(srow + 64) * Ci + kel;
  const int aoff = (wm * 64 + (l & 15)) * 32 + (l >> 4) * 8;
  const int boff = (wn * 64 + (l & 15)) * 32 + (l >> 4) * 8;
  f32x4 acc[4][4] = {};
  for (int kb = 0; kb < Ci; kb += 32) {
    __syncthreads();
    gload16(Ap + kb,  AsB);
    gload16(Ap2 + kb, AsB + 4096);
#pragma unroll
    for (int s = 0; s < 2; ++s) {
      const int slot = s * 256 + tid;
      const int row = slot >> 2, kq = slot & 3;
      const int tok = n0 + row;
      float sum[8] = {};
      if (tok < 224) {
        const u16* p = Bz + (size_t)tok * 1024 + kb + kq * 8;
#pragma unroll
        for (int hh = 0; hh < 4; ++hh) {
          const bf16x8 v = *(const bf16x8*)(p + (size_t)hh * 229376);
#pragma unroll
          for (int e = 0; e < 8; ++e) sum[e] += bf2f((u16)v[e]);
        }
      }
      bf16x8 o;
#pragma unroll
      for (int e = 0; e < 8; ++e) o[e] = (short)f2bf(sum[e] * 0.25f);
      *(bf16x8*)(Bs + row * 32 + kq * 8) = o;
    }
    __syncthreads();
    bf16x8 av[4], bv[4];
#pragma unroll
    for (int i = 0; i < 4; ++i) {
      av[i] = *(const bf16x8*)(As + aoff + i * 16 * 32);
      bv[i] = *(const bf16x8*)(Bs + boff + i * 16 * 32);
    }
#pragma unroll
    for (int i = 0; i < 4; ++i)
#pragma unroll
      for (int j = 0; j < 4; ++j)
        acc[i][j] = __builtin_amdgcn_mfma_f32_16x16x32_bf16(av[i], bv[j], acc[i][j], 0, 0, 0);
  }
  float* O = out + ob;
  const int gb = b0 + lb;
#pragma unroll
  for (int i = 0; i < 4; ++i) {
    const int cp0 = mt * 128 + wm * 64 + i * 16 + (l >> 4) * 4;
    if (cp0 >= Ci) continue;
#pragma unroll
    for (int j = 0; j < 4; ++j) {
      const int n = n0 + wn * 64 + j * 16 + (l & 15);
      if (n < 196)
        *(f32x4*)(O + ((size_t)gb * 196 + n) * Ci + cp0) = acc[i][j];
    }
  }
}

// ---------------------------------------------------------------------------
extern "C" void kernel_launch(void* const* d_in, const int* in_sizes, int n_in,
                              void* d_out, int out_size, void* d_ws, size_t ws_size,
                              hipStream_t stream)
{
  const float* eall = (const float*)d_in[4];
  const float* Wq1 = (const float*)d_in[5];
  const float* Wq2 = (const float*)d_in[6];
  const float* Wq3 = (const float*)d_in[7];
  const float* Wq4 = (const float*)d_in[8];
  const float* Wk  = (const float*)d_in[9];
  const float* Wv  = (const float*)d_in[10];
  const float* Wo1 = (const float*)d_in[11];
  const float* Wo2 = (const float*)d_in[12];
  const float* Wo3 = (const float*)d_in[13];
  const float* Wo4 = (const float*)d_in[14];
  float* out = (float*)d_out;

  char* p = (char*)d_ws;
  auto alloc = [&](size_t bytes) -> void* {
    void* r = p; p += (bytes + 255) & ~(size_t)255; return r;
  };
  u16* embA = (u16*)alloc((size_t)7168 * 960 * 2);
  u16* WkB  = (u16*)alloc((size_t)4 * 1024 * 960 * 2);
  u16* WvB  = (u16*)alloc((size_t)4 * 1024 * 960 * 2);
  u16* WqB  = (u16*)alloc((size_t)4 * 352256 * 2);
  u16* WoB  = (u16*)alloc((size_t)352256 * 2);
  const size_t persist = (size_t)(p - (char*)d_ws);
  const size_t perLB = (size_t)1835008 * 2 + 2097152 + 458752 + 1835008 + 64 + 2048;
  int Bc = 8;
  if      (persist + 32 * perLB <= ws_size) Bc = 32;
  else if (persist + 16 * perLB <= ws_size) Bc = 16;
  const int NB = Bc * 224;
  const int Z = Bc * 4;

  u16* Kt  = (u16*)alloc((size_t)4 * 1024 * NB * 2);
  u16* Qt  = (u16*)alloc((size_t)4 * 1024 * NB * 2);
  u16* V   = (u16*)alloc((size_t)Bc * 4 * 256 * 1024 * 2);
  u16* Gk  = (u16*)alloc((size_t)Bc * 4 * 256 * 224 * 2);
  u16* ctxh = (u16*)alloc((size_t)Bc * 4 * 229376 * 2);
  float* stats = (float*)alloc((size_t)Bc * 16 * 4);

  const dim3 blk(256);
  k_cvt<<<dim3(64480), blk, 0, stream>>>(eall, Wq1, Wq2, Wq3, Wq4, Wk, Wv,
                                         Wo1, Wo2, Wo3, Wo4,
                                         embA, WkB, WvB, WqB, WoB);

  const int NT = NB / 128;
  for (int b0 = 0; b0 < 32; b0 += Bc) {
    (void)hipMemsetAsync(stats, 0, (size_t)Bc * 16 * 4, stream);
    k_kt<<<dim3(8, NT, 4), blk, 0, stream>>>(embA, WkB, Kt, b0, NB);
    k_v <<<dim3(NT, 8, 4), blk, 0, stream>>>(embA, WvB, V, b0, NB);
    k_q <<<dim3(NT, 8, 4), blk, 0, stream>>>(embA, WqB, Qt, b0, NB);
    k_gk<<<dim3(2, 2, Z), blk, 0, stream>>>(Kt, Gk, NB);
    k_qgq<<<dim3(2, 8, Z), blk, 0, stream>>>(Qt, Gk, stats, NB);
    k_att<<<dim3(Z, 15), blk, 0, stream>>>(Qt, Kt, V, stats, ctxh, NB);
    k_o <<<dim3(8, 2, Bc), blk, 0, stream>>>(ctxh, WoB, out, b0);
  }
}

// Round 15
// 784.424 us; speedup vs baseline: 1.3776x; 1.0931x over previous
//
#include <hip/hip_runtime.h>
#include <math.h>

typedef __attribute__((ext_vector_type(8))) short bf16x8;   // 8 bf16 in 4 VGPRs
typedef __attribute__((ext_vector_type(4))) float f32x4;
typedef unsigned short u16;

__device__ __forceinline__ u16 f2bf(float f) {
  unsigned u = __float_as_uint(f);
  return (u16)((u + 0x7FFFu + ((u >> 16) & 1u)) >> 16);   // RNE
}
__device__ __forceinline__ float bf2f(u16 h) {
  return __uint_as_float(((unsigned)h) << 16);
}

__device__ __forceinline__ void gload16(const u16* g, void* lds) {
  __builtin_amdgcn_global_load_lds(
      (const __attribute__((address_space(1))) unsigned int*)g,
      (__attribute__((address_space(3))) unsigned int*)lds, 16, 0, 0);
}

// ---------------------------------------------------------------------------
// MFMA core (proven): 128x128 tile, BK=32, 256 threads (4 waves = 2x2
// quadrants of 4x4 16x16x32 fragments). K mult of 32; padded buffers.
// ---------------------------------------------------------------------------
__device__ __forceinline__ void mfma_core(
    const u16* __restrict__ A, int lda,
    const u16* __restrict__ B, int ldb,
    int K, f32x4 (&acc)[4][4], u16* As, u16* Bs)
{
  const int tid = threadIdx.x;
  const int l = tid & 63, w = tid >> 6;
  const int srow = w * 16 + (l >> 2);
  const int kel  = (l & 3) * 8;
  char* AsB = (char*)As + w * 1024;
  char* BsB = (char*)Bs + w * 1024;
  const u16* Ap  = A + (size_t)srow * lda + kel;
  const u16* Ap2 = A + (size_t)(srow + 64) * lda + kel;
  const u16* Bp  = B + (size_t)srow * ldb + kel;
  const u16* Bp2 = B + (size_t)(srow + 64) * ldb + kel;
  const int wm = w >> 1, wn = w & 1;
  const int aoff = (wm * 64 + (l & 15)) * 32 + (l >> 4) * 8;
  const int boff = (wn * 64 + (l & 15)) * 32 + (l >> 4) * 8;
  for (int kb = 0; kb < K; kb += 32) {
    __syncthreads();
    gload16(Ap + kb,  AsB);
    gload16(Ap2 + kb, AsB + 4096);
    gload16(Bp + kb,  BsB);
    gload16(Bp2 + kb, BsB + 4096);
    __syncthreads();
    bf16x8 av[4], bv[4];
#pragma unroll
    for (int i = 0; i < 4; ++i) {
      av[i] = *(const bf16x8*)(As + aoff + i * 16 * 32);
      bv[i] = *(const bf16x8*)(Bs + boff + i * 16 * 32);
    }
#pragma unroll
    for (int i = 0; i < 4; ++i)
#pragma unroll
      for (int j = 0; j < 4; ++j)
        acc[i][j] = __builtin_amdgcn_mfma_f32_16x16x32_bf16(av[i], bv[j], acc[i][j], 0, 0, 0);
  }
}

// ---------------------------------------------------------------------------
// One-shot pad/convert of all inputs (11 segments, hardcoded boundaries).
// ---------------------------------------------------------------------------
__global__ __launch_bounds__(256) void k_cvt(
    const float* __restrict__ eall,
    const float* __restrict__ Wq1, const float* __restrict__ Wq2,
    const float* __restrict__ Wq3, const float* __restrict__ Wq4,
    const float* __restrict__ Wk, const float* __restrict__ Wv,
    const float* __restrict__ Wo1, const float* __restrict__ Wo2,
    const float* __restrict__ Wo3, const float* __restrict__ Wo4,
    u16* __restrict__ embA, u16* __restrict__ WkB, u16* __restrict__ WvB,
    u16* __restrict__ WqB, u16* __restrict__ WoB)
{
  long long idx = (long long)blockIdx.x * 256 + threadIdx.x;
  const float* src; u16* dst; int srcR, dstR, C; long long stride, off, loc;
  if (idx < 6881280LL)       { loc = idx;               src=eall; dst=embA; srcR=196; dstR=224;  C=960; stride=215040; off=0; }
  else if (idx < 10813440LL) { loc = idx - 6881280LL;   src=Wk;   dst=WkB;  srcR=960; dstR=1024; C=960; stride=983040; off=0; }
  else if (idx < 14745600LL) { loc = idx - 10813440LL;  src=Wv;   dst=WvB;  srcR=960; dstR=1024; C=960; stride=983040; off=0; }
  else if (idx < 14778368LL) { loc = idx - 14745600LL;  src=Wq1;  dst=WqB;  srcR=64;  dstR=128;  C=64;  stride=352256; off=0; }
  else if (idx < 14843904LL) { loc = idx - 14778368LL;  src=Wq2;  dst=WqB;  srcR=128; dstR=128;  C=128; stride=352256; off=8192; }
  else if (idx < 15106048LL) { loc = idx - 14843904LL;  src=Wq3;  dst=WqB;  srcR=256; dstR=256;  C=256; stride=352256; off=24576; }
  else if (idx < 16154624LL) { loc = idx - 15106048LL;  src=Wq4;  dst=WqB;  srcR=512; dstR=512;  C=512; stride=352256; off=90112; }
  else if (idx < 16162816LL) { loc = idx - 16154624LL;  src=Wo1;  dst=WoB;  srcR=64;  dstR=128;  C=64;  stride=0; off=0; }
  else if (idx < 16179200LL) { loc = idx - 16162816LL;  src=Wo2;  dst=WoB;  srcR=128; dstR=128;  C=128; stride=0; off=8192; }
  else if (idx < 16244736LL) { loc = idx - 16179200LL;  src=Wo3;  dst=WoB;  srcR=256; dstR=256;  C=256; stride=0; off=24576; }
  else if (idx < 16506880LL) { loc = idx - 16244736LL;  src=Wo4;  dst=WoB;  srcR=512; dstR=512;  C=512; stride=0; off=90112; }
  else return;
  const long long per = (long long)dstR * C;
  const int g = (int)(loc / per);
  const int r2 = (int)(loc % per);
  const int rr = r2 / C, c = r2 - rr * C;
  const float v = (rr < srcR) ? src[((long long)g * srcR + rr) * C + c] : 0.f;
  dst[g * stride + off + (long long)rr * C + c] = f2bf(v);
}

// Kt[h][o(1024)][NB] = Wk[h] x embA^T
__global__ __launch_bounds__(256) void k_kt(const u16* __restrict__ embA,
    const u16* __restrict__ WkB, u16* __restrict__ Kt, int b0, int NB)
{
  __shared__ u16 As[128 * 32], Bs[128 * 32];
  const int h = blockIdx.z;
  const int m0 = blockIdx.y * 128, n0 = blockIdx.x * 128;
  const u16* A = WkB + (size_t)h * 1024 * 960 + (size_t)m0 * 960;
  const u16* B = embA + (size_t)(b0 * 224 + n0) * 960;
  f32x4 acc[4][4] = {};
  mfma_core(A, 960, B, 960, 960, acc, As, Bs);
  const int tid = threadIdx.x, l = tid & 63, w = tid >> 6, wm = w >> 1, wn = w & 1;
  u16* C = Kt + (size_t)h * 1024 * NB;
#pragma unroll
  for (int i = 0; i < 4; ++i) {
    const int gm0 = m0 + wm * 64 + i * 16 + (l >> 4) * 4;
#pragma unroll
    for (int j = 0; j < 4; ++j) {
      const int n = n0 + wn * 64 + j * 16 + (l & 15);
#pragma unroll
      for (int r = 0; r < 4; ++r)
        C[(size_t)(gm0 + r) * NB + n] = f2bf(acc[i][j][r]);
    }
  }
}

// V[lb][h][n(256 pad)][o(1024)] = embA x Wv[h]^T
__global__ __launch_bounds__(256) void k_v(const u16* __restrict__ embA,
    const u16* __restrict__ WvB, u16* __restrict__ V, int b0, int NB)
{
  __shared__ u16 As[128 * 32], Bs[128 * 32];
  const int h = blockIdx.z;
  const int m0 = blockIdx.y * 128, n0 = blockIdx.x * 128;
  const u16* A = embA + (size_t)(b0 * 224 + m0) * 960;
  const u16* B = WvB + (size_t)h * 1024 * 960 + (size_t)n0 * 960;
  f32x4 acc[4][4] = {};
  mfma_core(A, 960, B, 960, 960, acc, As, Bs);
  const int tid = threadIdx.x, l = tid & 63, w = tid >> 6, wm = w >> 1, wn = w & 1;
#pragma unroll
  for (int i = 0; i < 4; ++i) {
    const int t0 = m0 + wm * 64 + i * 16 + (l >> 4) * 4;
#pragma unroll
    for (int r = 0; r < 4; ++r) {
      const int t = t0 + r;
      const int lb = t / 224, n = t - lb * 224;
      u16* C = V + ((size_t)(lb * 4 + h) * 256 + n) * 1024;
#pragma unroll
      for (int j = 0; j < 4; ++j) {
        const int col = n0 + wn * 64 + j * 16 + (l & 15);
        C[col] = f2bf(acc[i][j][r]);
      }
    }
  }
}

// Qt[h][ccat(1024)][NB] = Wq_br[h] x emb_br^T  (branch slices read from embA)
__global__ __launch_bounds__(256) void k_q(const u16* __restrict__ embA,
    const u16* __restrict__ WqB, u16* __restrict__ Qt, int b0, int NB)
{
  __shared__ u16 As[128 * 32], Bs[128 * 32];
  const int h = blockIdx.z;
  const int y = blockIdx.y;
  const int br = (y == 0) ? 0 : (y == 1) ? 1 : (y < 4) ? 2 : 3;
  const int mt = (y <= 1) ? 0 : (y < 4) ? (y - 2) : (y - 4);
  const int Ci = 64 << br;
  const int coff = (br == 0) ? 0 : (br == 1) ? 64 : (br == 2) ? 192 : 448;
  const int wqo = (br == 0) ? 0 : (br == 1) ? 8192 : (br == 2) ? 24576 : 90112;
  const int n0 = blockIdx.x * 128;
  const u16* A = WqB + (size_t)h * 352256 + wqo + (size_t)mt * 128 * Ci;
  const u16* B = embA + (size_t)(b0 * 224 + n0) * 960 + coff;
  f32x4 acc[4][4] = {};
  mfma_core(A, Ci, B, 960, Ci, acc, As, Bs);
  const int tid = threadIdx.x, l = tid & 63, w = tid >> 6, wm = w >> 1, wn = w & 1;
  u16* C = Qt + (size_t)h * 1024 * NB;
#pragma unroll
  for (int i = 0; i < 4; ++i) {
    const int lr0 = mt * 128 + wm * 64 + i * 16 + (l >> 4) * 4;
#pragma unroll
    for (int j = 0; j < 4; ++j) {
      const int n = n0 + wn * 64 + j * 16 + (l & 15);
#pragma unroll
      for (int r = 0; r < 4; ++r)
        if (lr0 + r < Ci)
          C[(size_t)(coff + lr0 + r) * NB + n] = f2bf(acc[i][j][r]);
    }
  }
}

// ---------------------------------------------------------------------------
// Gk[z][n'(256 rows, 224 used)][n 224] bf16 = sum_o Kt[o,n']Kt[o,n].
// o-loop 960 (rows 960..1023 of Kt are exact zeros -- skip them).
// ---------------------------------------------------------------------------
#define TS_LD 72
__global__ __launch_bounds__(256) void k_gk(const u16* __restrict__ Kt,
                                            u16* __restrict__ Gk, int NB)
{
  __shared__ u16 TsA[128 * TS_LD], TsB[128 * TS_LD];
  const int z = blockIdx.z, lb = z >> 2, h = z & 3;
  const int n0a = blockIdx.y * 96, n0b = blockIdx.x * 96;
  const u16* Kz = Kt + (size_t)h * 1024 * NB + lb * 224;
  const int tid = threadIdx.x, l = tid & 63, w = tid >> 6, wm = w >> 1, wn = w & 1;
  f32x4 acc[4][4] = {};
  for (int o0 = 0; o0 < 960; o0 += 64) {
    __syncthreads();
#pragma unroll
    for (int it = 0; it < 16; ++it) {
      const int e = it * 256 + tid;
      const int o = e >> 6, np = e & 63;
      const unsigned va = *(const unsigned*)(Kz + (size_t)(o0 + o) * NB + n0a + np * 2);
      const unsigned vb = *(const unsigned*)(Kz + (size_t)(o0 + o) * NB + n0b + np * 2);
      const int o8 = o >> 3, oe = o & 7;
      const int r0 = np * 2, r1 = r0 + 1;
      TsA[r0 * TS_LD + (((o8 ^ (r0 & 7)) << 3) | oe)] = (u16)(va & 0xffff);
      TsA[r1 * TS_LD + (((o8 ^ (r1 & 7)) << 3) | oe)] = (u16)(va >> 16);
      TsB[r0 * TS_LD + (((o8 ^ (r0 & 7)) << 3) | oe)] = (u16)(vb & 0xffff);
      TsB[r1 * TS_LD + (((o8 ^ (r1 & 7)) << 3) | oe)] = (u16)(vb >> 16);
    }
    __syncthreads();
#pragma unroll
    for (int ks = 0; ks < 2; ++ks) {
      bf16x8 av[4], bv[4];
#pragma unroll
      for (int i = 0; i < 4; ++i) {
        const int ra = wm * 64 + i * 16 + (l & 15);
        av[i] = *(const bf16x8*)(TsA + ra * TS_LD + (((ks * 4 + (l >> 4)) ^ (ra & 7)) << 3));
        const int rb = wn * 64 + i * 16 + (l & 15);
        bv[i] = *(const bf16x8*)(TsB + rb * TS_LD + (((ks * 4 + (l >> 4)) ^ (rb & 7)) << 3));
      }
#pragma unroll
      for (int i = 0; i < 4; ++i)
#pragma unroll
        for (int j = 0; j < 4; ++j)
          acc[i][j] = __builtin_amdgcn_mfma_f32_16x16x32_bf16(av[i], bv[j], acc[i][j], 0, 0, 0);
    }
  }
  u16* G = Gk + (size_t)z * 256 * 224;
#pragma unroll
  for (int i = 0; i < 4; ++i) {
    const int ra0 = n0a + wm * 64 + i * 16 + (l >> 4) * 4;
#pragma unroll
    for (int j = 0; j < 4; ++j) {
      const int cb = n0b + wn * 64 + j * 16 + (l & 15);
#pragma unroll
      for (int r = 0; r < 4; ++r)
        G[(size_t)(ra0 + r) * 224 + cb] = f2bf(acc[i][j][r]);
    }
  }
}

// ---------------------------------------------------------------------------
// sumsq per (z, branch): Y = Qt_tile x Gk (mfma_core), then dot rows with Qt.
// ---------------------------------------------------------------------------
__global__ __launch_bounds__(256) void k_qgq(const u16* __restrict__ Qt,
    const u16* __restrict__ Gk, float* __restrict__ stats, int NB)
{
  __shared__ u16 As[128 * 32], Bs[128 * 32];
  __shared__ float sb[4];
  const int z = blockIdx.z, lb = z >> 2, h = z & 3;
  const int m0 = blockIdx.y * 128;
  const int tx = blockIdx.x;
  const int tid = threadIdx.x;
  if (tid < 4) sb[tid] = 0.f;
  const u16* A = Qt + (size_t)h * 1024 * NB + (size_t)m0 * NB + lb * 224;
  const u16* B = Gk + (size_t)z * 256 * 224 + (size_t)(tx * 96) * 224;
  f32x4 acc[4][4] = {};
  mfma_core(A, NB, B, 224, 224, acc, As, Bs);
  const int l = tid & 63, w = tid >> 6, wm = w >> 1, wn = w & 1;
  const u16* Qbase = Qt + (size_t)h * 1024 * NB + lb * 224;
  float part[4]; int pbr[4]; bool ok[4];
#pragma unroll
  for (int i = 0; i < 4; ++i) {
    const int gm0 = m0 + wm * 64 + i * 16 + (l >> 4) * 4;
    pbr[i] = (gm0 < 64) ? 0 : (gm0 < 192) ? 1 : (gm0 < 448) ? 2 : 3;
    ok[i] = (gm0 < 960);
    float s = 0.f;
    if (ok[i]) {
#pragma unroll
      for (int j = 0; j < 4; ++j) {
        const int col = tx * 96 + wn * 64 + j * 16 + (l & 15);
        if (tx == 1 && col < 128) continue;
#pragma unroll
        for (int r = 0; r < 4; ++r)
          s += acc[i][j][r] * bf2f(Qbase[(size_t)(gm0 + r) * NB + col]);
      }
    }
    part[i] = s;
  }
  __syncthreads();
#pragma unroll
  for (int i = 0; i < 4; ++i)
    if (ok[i]) atomicAdd(&sb[pbr[i]], part[i]);
  __syncthreads();
  if (tid < 4) atomicAdd(stats + (size_t)z * 4 + tid, sb[tid]);
}

// ---------------------------------------------------------------------------
// Fused attention v3 (R8, best measured: 106us): per (z, ct of 64 c-rows).
// Q in registers. Per 64-o chunk: gload_lds-stage K[64][232] + V[256][72]
// -> barrier -> 28 S-MFMAs -> exp -> Ps -> barrier -> 28 PV-MFMAs -> barrier.
// LDS ~79KB (2 blocks/CU, VGPR 124 no-spill).
// ---------------------------------------------------------------------------
#define KS_LD 232
#define VS_LD 72
#define PP_LD 72
__global__ __launch_bounds__(256, 2) void k_att(
    const u16* __restrict__ Qt, const u16* __restrict__ Kt,
    const u16* __restrict__ V, const float* __restrict__ stats,
    u16* __restrict__ ctxh, int NB)
{
  __shared__ u16 Ks[16384];          // 64 rows x 232 stride (+ tail pad)
  __shared__ u16 Vs[18432];          // 256 rows x 72 stride
  __shared__ u16 Ps[64 * PP_LD];
  __shared__ float rsum[64];
  const int z = blockIdx.x, ct = blockIdx.y;
  const int lb = z >> 2, h = z & 3;
  const int c0 = ct * 64;
  const int tid = threadIdx.x, l = tid & 63, w = tid >> 6;
  const int wm = w >> 1, wn = w & 1;
  const int br = (c0 < 64) ? 0 : (c0 < 192) ? 1 : (c0 < 448) ? 2 : 3;
  const float scale = 0.03227486121839514f;   // 1/sqrt(960)
  const float cnt = (float)(64 << br) * 960.f;
  const float var = stats[(size_t)z * 4 + br] * scale * scale / cnt;
  const float cs = scale * rsqrtf(var + 1e-5f);

  const u16* Qz = Qt + (size_t)h * 1024 * NB + (size_t)c0 * NB + lb * 224;
  const u16* Kz = Kt + (size_t)h * 1024 * NB + lb * 224;
  const u16* Vz = V + (size_t)z * 256 * 1024;

  // Q fragments in registers: this wave's 32 c-rows (wm half), K=224
  bf16x8 qa[2][7];
#pragma unroll
  for (int i = 0; i < 2; ++i)
#pragma unroll
    for (int ks = 0; ks < 7; ++ks)
      qa[i][ks] = *(const bf16x8*)(Qz + (size_t)(wm * 32 + i * 16 + (l & 15)) * NB
                                   + ks * 32 + (l >> 4) * 8);
  if (tid < 64) rsum[tid] = 0.f;

  // Precomputed per-lane staging source pointers (advance per chunk).
  const u16* kp[8];
#pragma unroll
  for (int c = 0; c < 8; ++c) {
    const int e = (c * 4 + w) * 512 + l * 8;
    const int row = e / KS_LD, col = e - row * KS_LD;   // col multiple of 8
    kp[c] = Kz + (size_t)row * NB + col;
  }
  const u16* vp[9];
#pragma unroll
  for (int c = 0; c < 9; ++c) {
    const int e = (c * 4 + w) * 512 + l * 8;
    const int row = e / VS_LD, col = e - row * VS_LD;
    vp[c] = Vz + (size_t)row * 1024 + col;
  }
  char* KsB = (char*)Ks + w * 1024;
  char* VsB = (char*)Vs + w * 1024;

  f32x4 cacc[7][2] = {};
  float rp[2][4] = {};

  for (int oc = 0; oc < 15; ++oc) {
    __syncthreads();               // prev chunk's PV done with Vs/Ps
    // ---- stage K chunk (8) + V chunk (9) via global_load_lds ----
#pragma unroll
    for (int c = 0; c < 8; ++c) {
      gload16(kp[c], KsB + c * 4096);
      kp[c] += (size_t)64 * NB;    // next 64 o-rows
    }
#pragma unroll
    for (int c = 0; c < 9; ++c) {
      gload16(vp[c], VsB + c * 4096);
      vp[c] += 64;                 // next 64 o-cols
    }
    __syncthreads();               // staging complete
    // ---- S chunk [64 c][64 o], K=224, operands from LDS/regs ----
    f32x4 sacc[2][2] = {};
#pragma unroll
    for (int ks = 0; ks < 7; ++ks) {
      bf16x8 kb[2];
#pragma unroll
      for (int j = 0; j < 2; ++j)
        kb[j] = *(const bf16x8*)(Ks + (wn * 32 + j * 16 + (l & 15)) * KS_LD
                                 + ks * 32 + (l >> 4) * 8);
#pragma unroll
      for (int i = 0; i < 2; ++i)
#pragma unroll
        for (int j = 0; j < 2; ++j)
          sacc[i][j] = __builtin_amdgcn_mfma_f32_16x16x32_bf16(qa[i][ks], kb[j], sacc[i][j], 0, 0, 0);
    }
    // ---- exp -> Ps + rowsum partials ----
#pragma unroll
    for (int i = 0; i < 2; ++i)
#pragma unroll
      for (int j = 0; j < 2; ++j)
#pragma unroll
        for (int r = 0; r < 4; ++r) {
          const float p = __expf(sacc[i][j][r] * cs);
          rp[i][r] += p;
          Ps[(wm * 32 + i * 16 + (l >> 4) * 4 + r) * PP_LD + wn * 32 + j * 16 + (l & 15)] = f2bf(p);
        }
    __syncthreads();               // Ps visible
    // ---- PV: ctx[224 n][64 c] += V . P^T (operands from LDS) ----
#pragma unroll
    for (int ks = 0; ks < 2; ++ks) {
      bf16x8 pv[2];
#pragma unroll
      for (int j = 0; j < 2; ++j)
        pv[j] = *(const bf16x8*)(Ps + (wn * 32 + j * 16 + (l & 15)) * PP_LD
                                 + ks * 32 + (l >> 4) * 8);
#pragma unroll
      for (int i2 = 0; i2 < 7; ++i2) {
        const bf16x8 av = *(const bf16x8*)(Vs + (wm * 112 + i2 * 16 + (l & 15)) * VS_LD
                                           + ks * 32 + (l >> 4) * 8);
#pragma unroll
        for (int j = 0; j < 2; ++j)
          cacc[i2][j] = __builtin_amdgcn_mfma_f32_16x16x32_bf16(av, pv[j], cacc[i2][j], 0, 0, 0);
      }
    }
  }
  __syncthreads();
  // rowsum: reduce over 16 lanes sharing a row, combine halves via LDS atomics
#pragma unroll
  for (int i = 0; i < 2; ++i)
#pragma unroll
    for (int r = 0; r < 4; ++r) {
      float v = rp[i][r];
      v += __shfl_xor(v, 1); v += __shfl_xor(v, 2);
      v += __shfl_xor(v, 4); v += __shfl_xor(v, 8);
      if ((l & 15) == 0) atomicAdd(&rsum[wm * 32 + i * 16 + (l >> 4) * 4 + r], v);
    }
  __syncthreads();
  float inv[2];
#pragma unroll
  for (int j = 0; j < 2; ++j)
    inv[j] = 1.f / rsum[wn * 32 + j * 16 + (l & 15)];

  // normalized bf16 ctx -> ctxh, staged via Cs (alias Ks), 2 passes x 112 rows
  u16* Cs = Ks;
  u16* dst = ctxh + (size_t)z * 229376 + c0;
#pragma unroll
  for (int pass = 0; pass < 2; ++pass) {
    if (wm == pass) {
#pragma unroll
      for (int i2 = 0; i2 < 7; ++i2)
#pragma unroll
        for (int j = 0; j < 2; ++j)
#pragma unroll
          for (int r = 0; r < 4; ++r)
            Cs[(i2 * 16 + (l >> 4) * 4 + r) * PP_LD + wn * 32 + j * 16 + (l & 15)]
                = f2bf(cacc[i2][j][r] * inv[j]);
    }
    __syncthreads();
    for (int u = tid; u < 112 * 8; u += 256) {
      const int row = u >> 3, c8 = u & 7;
      *(uint4*)(dst + (size_t)(pass * 112 + row) * 1024 + c8 * 8) =
          *(const uint4*)(Cs + row * PP_LD + c8 * 8);
    }
    __syncthreads();
  }
}

// ctx[lb][n][c] = bf16( 0.25 * sum_h ctxh[lb*4+h][n][c] )
__global__ __launch_bounds__(256) void k_ctxred(const u16* __restrict__ ctxh,
    u16* __restrict__ ctx, int Bc)
{
  const long long i8 = ((long long)blockIdx.x * 256 + threadIdx.x) * 8;
  if (i8 >= (long long)Bc * 229376) return;
  const int lb = (int)(i8 / 229376);
  const int off = (int)(i8 - (long long)lb * 229376);
  const u16* p = ctxh + (size_t)lb * 4 * 229376 + off;
  float s[8] = {};
#pragma unroll
  for (int h = 0; h < 4; ++h) {
    bf16x8 v = *(const bf16x8*)(p + (size_t)h * 229376);
#pragma unroll
    for (int i = 0; i < 8; ++i) s[i] += bf2f((u16)v[i]);
  }
  bf16x8 o;
#pragma unroll
  for (int i = 0; i < 8; ++i) o[i] = (short)f2bf(s[i] * 0.25f);
  *(bf16x8*)(ctx + (size_t)lb * 262144 + off) = o;
}

// O_br[b][n][c'] = ctx[b][n, coff:coff+Ci] . Wo_br^T   (f32 to d_out)
__global__ __launch_bounds__(256) void k_o(const u16* __restrict__ ctx,
    const u16* __restrict__ WoB, float* __restrict__ out, int b0)
{
  __shared__ u16 As[128 * 32], Bs[128 * 32];
  const int lb = blockIdx.z;
  const int x = blockIdx.x;
  const int br = (x == 0) ? 0 : (x == 1) ? 1 : (x < 4) ? 2 : 3;
  const int nt = (x <= 1) ? 0 : (x < 4) ? (x - 2) : (x - 4);
  const int Ci = 64 << br;
  const int coff = (br == 0) ? 0 : (br == 1) ? 64 : (br == 2) ? 192 : 448;
  const int woo = (br == 0) ? 0 : (br == 1) ? 8192 : (br == 2) ? 24576 : 90112;
  const long long ob = (br == 0) ? 0LL : (br == 1) ? 401408LL : (br == 2) ? 1204224LL : 2809856LL;
  const int m0 = blockIdx.y * 128;
  const u16* A = ctx + (size_t)lb * 262144 + (size_t)m0 * 1024 + coff;
  const u16* B = WoB + woo + (size_t)nt * 128 * Ci;
  f32x4 acc[4][4] = {};
  mfma_core(A, 1024, B, Ci, Ci, acc, As, Bs);
  const int tid = threadIdx.x, l = tid & 63, w = tid >> 6, wm = w >> 1, wn = w & 1;
  float* O = out + ob;
  const int gb = b0 + lb;
#pragma unroll
  for (int i = 0; i < 4; ++i) {
    const int row0 = m0 + wm * 64 + i * 16 + (l >> 4) * 4;
#pragma unroll
    for (int j = 0; j < 4; ++j) {
      const int cg = nt * 128 + wn * 64 + j * 16 + (l & 15);
#pragma unroll
      for (int r = 0; r < 4; ++r) {
        const int row = row0 + r;
        if (row < 196 && cg < Ci)
          O[((size_t)gb * 196 + row) * Ci + cg] = acc[i][j][r];
      }
    }
  }
}

// ---------------------------------------------------------------------------
extern "C" void kernel_launch(void* const* d_in, const int* in_sizes, int n_in,
                              void* d_out, int out_size, void* d_ws, size_t ws_size,
                              hipStream_t stream)
{
  const float* eall = (const float*)d_in[4];
  const float* Wq1 = (const float*)d_in[5];
  const float* Wq2 = (const float*)d_in[6];
  const float* Wq3 = (const float*)d_in[7];
  const float* Wq4 = (const float*)d_in[8];
  const float* Wk  = (const float*)d_in[9];
  const float* Wv  = (const float*)d_in[10];
  const float* Wo1 = (const float*)d_in[11];
  const float* Wo2 = (const float*)d_in[12];
  const float* Wo3 = (const float*)d_in[13];
  const float* Wo4 = (const float*)d_in[14];
  float* out = (float*)d_out;

  char* p = (char*)d_ws;
  auto alloc = [&](size_t bytes) -> void* {
    void* r = p; p += (bytes + 255) & ~(size_t)255; return r;
  };
  u16* embA = (u16*)alloc((size_t)7168 * 960 * 2);
  u16* WkB  = (u16*)alloc((size_t)4 * 1024 * 960 * 2);
  u16* WvB  = (u16*)alloc((size_t)4 * 1024 * 960 * 2);
  u16* WqB  = (u16*)alloc((size_t)4 * 352256 * 2);
  u16* WoB  = (u16*)alloc((size_t)352256 * 2);
  const size_t persist = (size_t)(p - (char*)d_ws);
  const size_t perLB = (size_t)1835008 * 2 + 2097152 + 458752 + 1835008 + 524288 + 64 + 2048;
  int Bc = 8;
  if      (persist + 32 * perLB <= ws_size) Bc = 32;
  else if (persist + 16 * perLB <= ws_size) Bc = 16;
  const int NB = Bc * 224;
  const int Z = Bc * 4;

  u16* Kt  = (u16*)alloc((size_t)4 * 1024 * NB * 2);
  u16* Qt  = (u16*)alloc((size_t)4 * 1024 * NB * 2);
  u16* V   = (u16*)alloc((size_t)Bc * 4 * 256 * 1024 * 2);
  u16* Gk  = (u16*)alloc((size_t)Bc * 4 * 256 * 224 * 2);
  u16* ctxh = (u16*)alloc((size_t)Bc * 4 * 229376 * 2);
  u16* ctx = (u16*)alloc((size_t)Bc * 262144 * 2);
  float* stats = (float*)alloc((size_t)Bc * 16 * 4);

  const dim3 blk(256);
  k_cvt<<<dim3(64480), blk, 0, stream>>>(eall, Wq1, Wq2, Wq3, Wq4, Wk, Wv,
                                         Wo1, Wo2, Wo3, Wo4,
                                         embA, WkB, WvB, WqB, WoB);

  const int NT = NB / 128;
  for (int b0 = 0; b0 < 32; b0 += Bc) {
    (void)hipMemsetAsync(stats, 0, (size_t)Bc * 16 * 4, stream);
    k_kt<<<dim3(NT, 8, 4), blk, 0, stream>>>(embA, WkB, Kt, b0, NB);
    k_v <<<dim3(8, NT, 4), blk, 0, stream>>>(embA, WvB, V, b0, NB);
    k_q <<<dim3(NT, 8, 4), blk, 0, stream>>>(embA, WqB, Qt, b0, NB);
    k_gk<<<dim3(2, 2, Z), blk, 0, stream>>>(Kt, Gk, NB);
    k_qgq<<<dim3(2, 8, Z), blk, 0, stream>>>(Qt, Gk, stats, NB);
    k_att<<<dim3(Z, 15), blk, 0, stream>>>(Qt, Kt, V, stats, ctxh, NB);
    k_ctxred<<<dim3((Bc * 229376 / 8 + 255) / 256), blk, 0, stream>>>(ctxh, ctx, Bc);
    k_o <<<dim3(8, 2, Bc), blk, 0, stream>>>(ctx, WoB, out, b0);
  }
}

// Round 16
// 765.300 us; speedup vs baseline: 1.4121x; 1.0250x over previous
//
#include <hip/hip_runtime.h>
#include <math.h>

typedef __attribute__((ext_vector_type(8))) short bf16x8;   // 8 bf16 in 4 VGPRs
typedef __attribute__((ext_vector_type(4))) float f32x4;
typedef unsigned short u16;

__device__ __forceinline__ u16 f2bf(float f) {
  unsigned u = __float_as_uint(f);
  return (u16)((u + 0x7FFFu + ((u >> 16) & 1u)) >> 16);   // RNE
}
__device__ __forceinline__ float bf2f(u16 h) {
  return __uint_as_float(((unsigned)h) << 16);
}

__device__ __forceinline__ void gload16(const u16* g, void* lds) {
  __builtin_amdgcn_global_load_lds(
      (const __attribute__((address_space(1))) unsigned int*)g,
      (__attribute__((address_space(3))) unsigned int*)lds, 16, 0, 0);
}

// ---------------------------------------------------------------------------
// MFMA core BK=32 (proven): 128x128 tile, 256 threads. K mult of 32.
// Used by k_qgq (K=224). As/Bs: 128*32 u16.
// ---------------------------------------------------------------------------
__device__ __forceinline__ void mfma_core(
    const u16* __restrict__ A, int lda,
    const u16* __restrict__ B, int ldb,
    int K, f32x4 (&acc)[4][4], u16* As, u16* Bs)
{
  const int tid = threadIdx.x;
  const int l = tid & 63, w = tid >> 6;
  const int srow = w * 16 + (l >> 2);
  const int kel  = (l & 3) * 8;
  char* AsB = (char*)As + w * 1024;
  char* BsB = (char*)Bs + w * 1024;
  const u16* Ap  = A + (size_t)srow * lda + kel;
  const u16* Ap2 = A + (size_t)(srow + 64) * lda + kel;
  const u16* Bp  = B + (size_t)srow * ldb + kel;
  const u16* Bp2 = B + (size_t)(srow + 64) * ldb + kel;
  const int wm = w >> 1, wn = w & 1;
  const int aoff = (wm * 64 + (l & 15)) * 32 + (l >> 4) * 8;
  const int boff = (wn * 64 + (l & 15)) * 32 + (l >> 4) * 8;
  for (int kb = 0; kb < K; kb += 32) {
    __syncthreads();
    gload16(Ap + kb,  AsB);
    gload16(Ap2 + kb, AsB + 4096);
    gload16(Bp + kb,  BsB);
    gload16(Bp2 + kb, BsB + 4096);
    __syncthreads();
    bf16x8 av[4], bv[4];
#pragma unroll
    for (int i = 0; i < 4; ++i) {
      av[i] = *(const bf16x8*)(As + aoff + i * 16 * 32);
      bv[i] = *(const bf16x8*)(Bs + boff + i * 16 * 32);
    }
#pragma unroll
    for (int i = 0; i < 4; ++i)
#pragma unroll
      for (int j = 0; j < 4; ++j)
        acc[i][j] = __builtin_amdgcn_mfma_f32_16x16x32_bf16(av[i], bv[j], acc[i][j], 0, 0, 0);
  }
}

// ---------------------------------------------------------------------------
// MFMA core BK=64: 32 MFMAs per barrier pair (half the drains of BK=32).
// K must be a multiple of 64. As/Bs: 128*64 u16 (two 32-k halves, half1 at
// +4096 u16). Used by k_kt/k_v/k_q/k_o.
// ---------------------------------------------------------------------------
__device__ __forceinline__ void mfma_core64(
    const u16* __restrict__ A, int lda,
    const u16* __restrict__ B, int ldb,
    int K, f32x4 (&acc)[4][4], u16* As, u16* Bs)
{
  const int tid = threadIdx.x;
  const int l = tid & 63, w = tid >> 6;
  const int srow = w * 16 + (l >> 2);
  const int kel  = (l & 3) * 8;
  char* AsB = (char*)As + w * 1024;
  char* BsB = (char*)Bs + w * 1024;
  const u16* Ap  = A + (size_t)srow * lda + kel;
  const u16* Ap2 = A + (size_t)(srow + 64) * lda + kel;
  const u16* Bp  = B + (size_t)srow * ldb + kel;
  const u16* Bp2 = B + (size_t)(srow + 64) * ldb + kel;
  const int wm = w >> 1, wn = w & 1;
  const int aoff = (wm * 64 + (l & 15)) * 32 + (l >> 4) * 8;
  const int boff = (wn * 64 + (l & 15)) * 32 + (l >> 4) * 8;
  for (int kb = 0; kb < K; kb += 64) {
    __syncthreads();
    gload16(Ap + kb,       AsB);
    gload16(Ap2 + kb,      AsB + 4096);
    gload16(Ap + kb + 32,  AsB + 8192);
    gload16(Ap2 + kb + 32, AsB + 12288);
    gload16(Bp + kb,       BsB);
    gload16(Bp2 + kb,      BsB + 4096);
    gload16(Bp + kb + 32,  BsB + 8192);
    gload16(Bp2 + kb + 32, BsB + 12288);
    __syncthreads();
#pragma unroll
    for (int ks = 0; ks < 2; ++ks) {
      bf16x8 av[4], bv[4];
#pragma unroll
      for (int i = 0; i < 4; ++i) {
        av[i] = *(const bf16x8*)(As + ks * 4096 + aoff + i * 16 * 32);
        bv[i] = *(const bf16x8*)(Bs + ks * 4096 + boff + i * 16 * 32);
      }
#pragma unroll
      for (int i = 0; i < 4; ++i)
#pragma unroll
        for (int j = 0; j < 4; ++j)
          acc[i][j] = __builtin_amdgcn_mfma_f32_16x16x32_bf16(av[i], bv[j], acc[i][j], 0, 0, 0);
    }
  }
}

// ---------------------------------------------------------------------------
// One-shot pad/convert of all inputs (11 segments, hardcoded boundaries).
// ---------------------------------------------------------------------------
__global__ __launch_bounds__(256) void k_cvt(
    const float* __restrict__ eall,
    const float* __restrict__ Wq1, const float* __restrict__ Wq2,
    const float* __restrict__ Wq3, const float* __restrict__ Wq4,
    const float* __restrict__ Wk, const float* __restrict__ Wv,
    const float* __restrict__ Wo1, const float* __restrict__ Wo2,
    const float* __restrict__ Wo3, const float* __restrict__ Wo4,
    u16* __restrict__ embA, u16* __restrict__ WkB, u16* __restrict__ WvB,
    u16* __restrict__ WqB, u16* __restrict__ WoB)
{
  long long idx = (long long)blockIdx.x * 256 + threadIdx.x;
  const float* src; u16* dst; int srcR, dstR, C; long long stride, off, loc;
  if (idx < 6881280LL)       { loc = idx;               src=eall; dst=embA; srcR=196; dstR=224;  C=960; stride=215040; off=0; }
  else if (idx < 10813440LL) { loc = idx - 6881280LL;   src=Wk;   dst=WkB;  srcR=960; dstR=1024; C=960; stride=983040; off=0; }
  else if (idx < 14745600LL) { loc = idx - 10813440LL;  src=Wv;   dst=WvB;  srcR=960; dstR=1024; C=960; stride=983040; off=0; }
  else if (idx < 14778368LL) { loc = idx - 14745600LL;  src=Wq1;  dst=WqB;  srcR=64;  dstR=128;  C=64;  stride=352256; off=0; }
  else if (idx < 14843904LL) { loc = idx - 14778368LL;  src=Wq2;  dst=WqB;  srcR=128; dstR=128;  C=128; stride=352256; off=8192; }
  else if (idx < 15106048LL) { loc = idx - 14843904LL;  src=Wq3;  dst=WqB;  srcR=256; dstR=256;  C=256; stride=352256; off=24576; }
  else if (idx < 16154624LL) { loc = idx - 15106048LL;  src=Wq4;  dst=WqB;  srcR=512; dstR=512;  C=512; stride=352256; off=90112; }
  else if (idx < 16162816LL) { loc = idx - 16154624LL;  src=Wo1;  dst=WoB;  srcR=64;  dstR=128;  C=64;  stride=0; off=0; }
  else if (idx < 16179200LL) { loc = idx - 16162816LL;  src=Wo2;  dst=WoB;  srcR=128; dstR=128;  C=128; stride=0; off=8192; }
  else if (idx < 16244736LL) { loc = idx - 16179200LL;  src=Wo3;  dst=WoB;  srcR=256; dstR=256;  C=256; stride=0; off=24576; }
  else if (idx < 16506880LL) { loc = idx - 16244736LL;  src=Wo4;  dst=WoB;  srcR=512; dstR=512;  C=512; stride=0; off=90112; }
  else return;
  const long long per = (long long)dstR * C;
  const int g = (int)(loc / per);
  const int r2 = (int)(loc % per);
  const int rr = r2 / C, c = r2 - rr * C;
  const float v = (rr < srcR) ? src[((long long)g * srcR + rr) * C + c] : 0.f;
  dst[g * stride + off + (long long)rr * C + c] = f2bf(v);
}

// Kt[h][o(1024)][NB] = Wk[h] x embA^T
__global__ __launch_bounds__(256) void k_kt(const u16* __restrict__ embA,
    const u16* __restrict__ WkB, u16* __restrict__ Kt, int b0, int NB)
{
  __shared__ u16 As[128 * 64], Bs[128 * 64];
  const int h = blockIdx.z;
  const int m0 = blockIdx.y * 128, n0 = blockIdx.x * 128;
  const u16* A = WkB + (size_t)h * 1024 * 960 + (size_t)m0 * 960;
  const u16* B = embA + (size_t)(b0 * 224 + n0) * 960;
  f32x4 acc[4][4] = {};
  mfma_core64(A, 960, B, 960, 960, acc, As, Bs);
  const int tid = threadIdx.x, l = tid & 63, w = tid >> 6, wm = w >> 1, wn = w & 1;
  u16* C = Kt + (size_t)h * 1024 * NB;
#pragma unroll
  for (int i = 0; i < 4; ++i) {
    const int gm0 = m0 + wm * 64 + i * 16 + (l >> 4) * 4;
#pragma unroll
    for (int j = 0; j < 4; ++j) {
      const int n = n0 + wn * 64 + j * 16 + (l & 15);
#pragma unroll
      for (int r = 0; r < 4; ++r)
        C[(size_t)(gm0 + r) * NB + n] = f2bf(acc[i][j][r]);
    }
  }
}

// V[lb][h][n(256 pad)][o(1024)] = embA x Wv[h]^T
__global__ __launch_bounds__(256) void k_v(const u16* __restrict__ embA,
    const u16* __restrict__ WvB, u16* __restrict__ V, int b0, int NB)
{
  __shared__ u16 As[128 * 64], Bs[128 * 64];
  const int h = blockIdx.z;
  const int m0 = blockIdx.y * 128, n0 = blockIdx.x * 128;
  const u16* A = embA + (size_t)(b0 * 224 + m0) * 960;
  const u16* B = WvB + (size_t)h * 1024 * 960 + (size_t)n0 * 960;
  f32x4 acc[4][4] = {};
  mfma_core64(A, 960, B, 960, 960, acc, As, Bs);
  const int tid = threadIdx.x, l = tid & 63, w = tid >> 6, wm = w >> 1, wn = w & 1;
#pragma unroll
  for (int i = 0; i < 4; ++i) {
    const int t0 = m0 + wm * 64 + i * 16 + (l >> 4) * 4;
#pragma unroll
    for (int r = 0; r < 4; ++r) {
      const int t = t0 + r;
      const int lb = t / 224, n = t - lb * 224;
      u16* C = V + ((size_t)(lb * 4 + h) * 256 + n) * 1024;
#pragma unroll
      for (int j = 0; j < 4; ++j) {
        const int col = n0 + wn * 64 + j * 16 + (l & 15);
        C[col] = f2bf(acc[i][j][r]);
      }
    }
  }
}

// Qt[h][ccat(1024)][NB] = Wq_br[h] x emb_br^T  (branch slices read from embA)
__global__ __launch_bounds__(256) void k_q(const u16* __restrict__ embA,
    const u16* __restrict__ WqB, u16* __restrict__ Qt, int b0, int NB)
{
  __shared__ u16 As[128 * 64], Bs[128 * 64];
  const int h = blockIdx.z;
  const int y = blockIdx.y;
  const int br = (y == 0) ? 0 : (y == 1) ? 1 : (y < 4) ? 2 : 3;
  const int mt = (y <= 1) ? 0 : (y < 4) ? (y - 2) : (y - 4);
  const int Ci = 64 << br;
  const int coff = (br == 0) ? 0 : (br == 1) ? 64 : (br == 2) ? 192 : 448;
  const int wqo = (br == 0) ? 0 : (br == 1) ? 8192 : (br == 2) ? 24576 : 90112;
  const int n0 = blockIdx.x * 128;
  const u16* A = WqB + (size_t)h * 352256 + wqo + (size_t)mt * 128 * Ci;
  const u16* B = embA + (size_t)(b0 * 224 + n0) * 960 + coff;
  f32x4 acc[4][4] = {};
  mfma_core64(A, Ci, B, 960, Ci, acc, As, Bs);
  const int tid = threadIdx.x, l = tid & 63, w = tid >> 6, wm = w >> 1, wn = w & 1;
  u16* C = Qt + (size_t)h * 1024 * NB;
#pragma unroll
  for (int i = 0; i < 4; ++i) {
    const int lr0 = mt * 128 + wm * 64 + i * 16 + (l >> 4) * 4;
#pragma unroll
    for (int j = 0; j < 4; ++j) {
      const int n = n0 + wn * 64 + j * 16 + (l & 15);
#pragma unroll
      for (int r = 0; r < 4; ++r)
        if (lr0 + r < Ci)
          C[(size_t)(coff + lr0 + r) * NB + n] = f2bf(acc[i][j][r]);
    }
  }
}

// ---------------------------------------------------------------------------
// Gk[z][n'(256 rows, 224 used)][n 224] bf16 = sum_o Kt[o,n']Kt[o,n].
// o-loop 960 (rows 960..1023 of Kt are exact zeros -- skip them).
// ---------------------------------------------------------------------------
#define TS_LD 72
__global__ __launch_bounds__(256) void k_gk(const u16* __restrict__ Kt,
                                            u16* __restrict__ Gk, int NB)
{
  __shared__ u16 TsA[128 * TS_LD], TsB[128 * TS_LD];
  const int z = blockIdx.z, lb = z >> 2, h = z & 3;
  const int n0a = blockIdx.y * 96, n0b = blockIdx.x * 96;
  const u16* Kz = Kt + (size_t)h * 1024 * NB + lb * 224;
  const int tid = threadIdx.x, l = tid & 63, w = tid >> 6, wm = w >> 1, wn = w & 1;
  f32x4 acc[4][4] = {};
  for (int o0 = 0; o0 < 960; o0 += 64) {
    __syncthreads();
#pragma unroll
    for (int it = 0; it < 16; ++it) {
      const int e = it * 256 + tid;
      const int o = e >> 6, np = e & 63;
      const unsigned va = *(const unsigned*)(Kz + (size_t)(o0 + o) * NB + n0a + np * 2);
      const unsigned vb = *(const unsigned*)(Kz + (size_t)(o0 + o) * NB + n0b + np * 2);
      const int o8 = o >> 3, oe = o & 7;
      const int r0 = np * 2, r1 = r0 + 1;
      TsA[r0 * TS_LD + (((o8 ^ (r0 & 7)) << 3) | oe)] = (u16)(va & 0xffff);
      TsA[r1 * TS_LD + (((o8 ^ (r1 & 7)) << 3) | oe)] = (u16)(va >> 16);
      TsB[r0 * TS_LD + (((o8 ^ (r0 & 7)) << 3) | oe)] = (u16)(vb & 0xffff);
      TsB[r1 * TS_LD + (((o8 ^ (r1 & 7)) << 3) | oe)] = (u16)(vb >> 16);
    }
    __syncthreads();
#pragma unroll
    for (int ks = 0; ks < 2; ++ks) {
      bf16x8 av[4], bv[4];
#pragma unroll
      for (int i = 0; i < 4; ++i) {
        const int ra = wm * 64 + i * 16 + (l & 15);
        av[i] = *(const bf16x8*)(TsA + ra * TS_LD + (((ks * 4 + (l >> 4)) ^ (ra & 7)) << 3));
        const int rb = wn * 64 + i * 16 + (l & 15);
        bv[i] = *(const bf16x8*)(TsB + rb * TS_LD + (((ks * 4 + (l >> 4)) ^ (rb & 7)) << 3));
      }
#pragma unroll
      for (int i = 0; i < 4; ++i)
#pragma unroll
        for (int j = 0; j < 4; ++j)
          acc[i][j] = __builtin_amdgcn_mfma_f32_16x16x32_bf16(av[i], bv[j], acc[i][j], 0, 0, 0);
    }
  }
  u16* G = Gk + (size_t)z * 256 * 224;
#pragma unroll
  for (int i = 0; i < 4; ++i) {
    const int ra0 = n0a + wm * 64 + i * 16 + (l >> 4) * 4;
#pragma unroll
    for (int j = 0; j < 4; ++j) {
      const int cb = n0b + wn * 64 + j * 16 + (l & 15);
#pragma unroll
      for (int r = 0; r < 4; ++r)
        G[(size_t)(ra0 + r) * 224 + cb] = f2bf(acc[i][j][r]);
    }
  }
}

// ---------------------------------------------------------------------------
// sumsq per (z, branch): Y = Qt_tile x Gk (BK=32 core, K=224), dot with Qt.
// ---------------------------------------------------------------------------
__global__ __launch_bounds__(256) void k_qgq(const u16* __restrict__ Qt,
    const u16* __restrict__ Gk, float* __restrict__ stats, int NB)
{
  __shared__ u16 As[128 * 32], Bs[128 * 32];
  __shared__ float sb[4];
  const int z = blockIdx.z, lb = z >> 2, h = z & 3;
  const int m0 = blockIdx.y * 128;
  const int tx = blockIdx.x;
  const int tid = threadIdx.x;
  if (tid < 4) sb[tid] = 0.f;
  const u16* A = Qt + (size_t)h * 1024 * NB + (size_t)m0 * NB + lb * 224;
  const u16* B = Gk + (size_t)z * 256 * 224 + (size_t)(tx * 96) * 224;
  f32x4 acc[4][4] = {};
  mfma_core(A, NB, B, 224, 224, acc, As, Bs);
  const int l = tid & 63, w = tid >> 6, wm = w >> 1, wn = w & 1;
  const u16* Qbase = Qt + (size_t)h * 1024 * NB + lb * 224;
  float part[4]; int pbr[4]; bool ok[4];
#pragma unroll
  for (int i = 0; i < 4; ++i) {
    const int gm0 = m0 + wm * 64 + i * 16 + (l >> 4) * 4;
    pbr[i] = (gm0 < 64) ? 0 : (gm0 < 192) ? 1 : (gm0 < 448) ? 2 : 3;
    ok[i] = (gm0 < 960);
    float s = 0.f;
    if (ok[i]) {
#pragma unroll
      for (int j = 0; j < 4; ++j) {
        const int col = tx * 96 + wn * 64 + j * 16 + (l & 15);
        if (tx == 1 && col < 128) continue;
#pragma unroll
        for (int r = 0; r < 4; ++r)
          s += acc[i][j][r] * bf2f(Qbase[(size_t)(gm0 + r) * NB + col]);
      }
    }
    part[i] = s;
  }
  __syncthreads();
#pragma unroll
  for (int i = 0; i < 4; ++i)
    if (ok[i]) atomicAdd(&sb[pbr[i]], part[i]);
  __syncthreads();
  if (tid < 4) atomicAdd(stats + (size_t)z * 4 + tid, sb[tid]);
}

// ---------------------------------------------------------------------------
// Fused attention v3 (R8, best measured: 106us): per (z, ct of 64 c-rows).
// ---------------------------------------------------------------------------
#define KS_LD 232
#define VS_LD 72
#define PP_LD 72
__global__ __launch_bounds__(256, 2) void k_att(
    const u16* __restrict__ Qt, const u16* __restrict__ Kt,
    const u16* __restrict__ V, const float* __restrict__ stats,
    u16* __restrict__ ctxh, int NB)
{
  __shared__ u16 Ks[16384];          // 64 rows x 232 stride (+ tail pad)
  __shared__ u16 Vs[18432];          // 256 rows x 72 stride
  __shared__ u16 Ps[64 * PP_LD];
  __shared__ float rsum[64];
  const int z = blockIdx.x, ct = blockIdx.y;
  const int lb = z >> 2, h = z & 3;
  const int c0 = ct * 64;
  const int tid = threadIdx.x, l = tid & 63, w = tid >> 6;
  const int wm = w >> 1, wn = w & 1;
  const int br = (c0 < 64) ? 0 : (c0 < 192) ? 1 : (c0 < 448) ? 2 : 3;
  const float scale = 0.03227486121839514f;   // 1/sqrt(960)
  const float cnt = (float)(64 << br) * 960.f;
  const float var = stats[(size_t)z * 4 + br] * scale * scale / cnt;
  const float cs = scale * rsqrtf(var + 1e-5f);

  const u16* Qz = Qt + (size_t)h * 1024 * NB + (size_t)c0 * NB + lb * 224;
  const u16* Kz = Kt + (size_t)h * 1024 * NB + lb * 224;
  const u16* Vz = V + (size_t)z * 256 * 1024;

  bf16x8 qa[2][7];
#pragma unroll
  for (int i = 0; i < 2; ++i)
#pragma unroll
    for (int ks = 0; ks < 7; ++ks)
      qa[i][ks] = *(const bf16x8*)(Qz + (size_t)(wm * 32 + i * 16 + (l & 15)) * NB
                                   + ks * 32 + (l >> 4) * 8);
  if (tid < 64) rsum[tid] = 0.f;

  const u16* kp[8];
#pragma unroll
  for (int c = 0; c < 8; ++c) {
    const int e = (c * 4 + w) * 512 + l * 8;
    const int row = e / KS_LD, col = e - row * KS_LD;
    kp[c] = Kz + (size_t)row * NB + col;
  }
  const u16* vp[9];
#pragma unroll
  for (int c = 0; c < 9; ++c) {
    const int e = (c * 4 + w) * 512 + l * 8;
    const int row = e / VS_LD, col = e - row * VS_LD;
    vp[c] = Vz + (size_t)row * 1024 + col;
  }
  char* KsB = (char*)Ks + w * 1024;
  char* VsB = (char*)Vs + w * 1024;

  f32x4 cacc[7][2] = {};
  float rp[2][4] = {};

  for (int oc = 0; oc < 15; ++oc) {
    __syncthreads();
#pragma unroll
    for (int c = 0; c < 8; ++c) {
      gload16(kp[c], KsB + c * 4096);
      kp[c] += (size_t)64 * NB;
    }
#pragma unroll
    for (int c = 0; c < 9; ++c) {
      gload16(vp[c], VsB + c * 4096);
      vp[c] += 64;
    }
    __syncthreads();
    f32x4 sacc[2][2] = {};
#pragma unroll
    for (int ks = 0; ks < 7; ++ks) {
      bf16x8 kb[2];
#pragma unroll
      for (int j = 0; j < 2; ++j)
        kb[j] = *(const bf16x8*)(Ks + (wn * 32 + j * 16 + (l & 15)) * KS_LD
                                 + ks * 32 + (l >> 4) * 8);
#pragma unroll
      for (int i = 0; i < 2; ++i)
#pragma unroll
        for (int j = 0; j < 2; ++j)
          sacc[i][j] = __builtin_amdgcn_mfma_f32_16x16x32_bf16(qa[i][ks], kb[j], sacc[i][j], 0, 0, 0);
    }
#pragma unroll
    for (int i = 0; i < 2; ++i)
#pragma unroll
      for (int j = 0; j < 2; ++j)
#pragma unroll
        for (int r = 0; r < 4; ++r) {
          const float p = __expf(sacc[i][j][r] * cs);
          rp[i][r] += p;
          Ps[(wm * 32 + i * 16 + (l >> 4) * 4 + r) * PP_LD + wn * 32 + j * 16 + (l & 15)] = f2bf(p);
        }
    __syncthreads();
#pragma unroll
    for (int ks = 0; ks < 2; ++ks) {
      bf16x8 pv[2];
#pragma unroll
      for (int j = 0; j < 2; ++j)
        pv[j] = *(const bf16x8*)(Ps + (wn * 32 + j * 16 + (l & 15)) * PP_LD
                                 + ks * 32 + (l >> 4) * 8);
#pragma unroll
      for (int i2 = 0; i2 < 7; ++i2) {
        const bf16x8 av = *(const bf16x8*)(Vs + (wm * 112 + i2 * 16 + (l & 15)) * VS_LD
                                           + ks * 32 + (l >> 4) * 8);
#pragma unroll
        for (int j = 0; j < 2; ++j)
          cacc[i2][j] = __builtin_amdgcn_mfma_f32_16x16x32_bf16(av, pv[j], cacc[i2][j], 0, 0, 0);
      }
    }
  }
  __syncthreads();
#pragma unroll
  for (int i = 0; i < 2; ++i)
#pragma unroll
    for (int r = 0; r < 4; ++r) {
      float v = rp[i][r];
      v += __shfl_xor(v, 1); v += __shfl_xor(v, 2);
      v += __shfl_xor(v, 4); v += __shfl_xor(v, 8);
      if ((l & 15) == 0) atomicAdd(&rsum[wm * 32 + i * 16 + (l >> 4) * 4 + r], v);
    }
  __syncthreads();
  float inv[2];
#pragma unroll
  for (int j = 0; j < 2; ++j)
    inv[j] = 1.f / rsum[wn * 32 + j * 16 + (l & 15)];

  u16* Cs = Ks;
  u16* dst = ctxh + (size_t)z * 229376 + c0;
#pragma unroll
  for (int pass = 0; pass < 2; ++pass) {
    if (wm == pass) {
#pragma unroll
      for (int i2 = 0; i2 < 7; ++i2)
#pragma unroll
        for (int j = 0; j < 2; ++j)
#pragma unroll
          for (int r = 0; r < 4; ++r)
            Cs[(i2 * 16 + (l >> 4) * 4 + r) * PP_LD + wn * 32 + j * 16 + (l & 15)]
                = f2bf(cacc[i2][j][r] * inv[j]);
    }
    __syncthreads();
    for (int u = tid; u < 112 * 8; u += 256) {
      const int row = u >> 3, c8 = u & 7;
      *(uint4*)(dst + (size_t)(pass * 112 + row) * 1024 + c8 * 8) =
          *(const uint4*)(Cs + row * PP_LD + c8 * 8);
    }
    __syncthreads();
  }
}

// ctx[lb][n][c] = bf16( 0.25 * sum_h ctxh[lb*4+h][n][c] )
__global__ __launch_bounds__(256) void k_ctxred(const u16* __restrict__ ctxh,
    u16* __restrict__ ctx, int Bc)
{
  const long long i8 = ((long long)blockIdx.x * 256 + threadIdx.x) * 8;
  if (i8 >= (long long)Bc * 229376) return;
  const int lb = (int)(i8 / 229376);
  const int off = (int)(i8 - (long long)lb * 229376);
  const u16* p = ctxh + (size_t)lb * 4 * 229376 + off;
  float s[8] = {};
#pragma unroll
  for (int h = 0; h < 4; ++h) {
    bf16x8 v = *(const bf16x8*)(p + (size_t)h * 229376);
#pragma unroll
    for (int i = 0; i < 8; ++i) s[i] += bf2f((u16)v[i]);
  }
  bf16x8 o;
#pragma unroll
  for (int i = 0; i < 8; ++i) o[i] = (short)f2bf(s[i] * 0.25f);
  *(bf16x8*)(ctx + (size_t)lb * 262144 + off) = o;
}

// O_br[b][n][c'] = ctx[b][n, coff:coff+Ci] . Wo_br^T   (f32 to d_out)
__global__ __launch_bounds__(256) void k_o(const u16* __restrict__ ctx,
    const u16* __restrict__ WoB, float* __restrict__ out, int b0)
{
  __shared__ u16 As[128 * 64], Bs[128 * 64];
  const int lb = blockIdx.z;
  const int x = blockIdx.x;
  const int br = (x == 0) ? 0 : (x == 1) ? 1 : (x < 4) ? 2 : 3;
  const int nt = (x <= 1) ? 0 : (x < 4) ? (x - 2) : (x - 4);
  const int Ci = 64 << br;
  const int coff = (br == 0) ? 0 : (br == 1) ? 64 : (br == 2) ? 192 : 448;
  const int woo = (br == 0) ? 0 : (br == 1) ? 8192 : (br == 2) ? 24576 : 90112;
  const long long ob = (br == 0) ? 0LL : (br == 1) ? 401408LL : (br == 2) ? 1204224LL : 2809856LL;
  const int m0 = blockIdx.y * 128;
  const u16* A = ctx + (size_t)lb * 262144 + (size_t)m0 * 1024 + coff;
  const u16* B = WoB + woo + (size_t)nt * 128 * Ci;
  f32x4 acc[4][4] = {};
  mfma_core64(A, 1024, B, Ci, Ci, acc, As, Bs);
  const int tid = threadIdx.x, l = tid & 63, w = tid >> 6, wm = w >> 1, wn = w & 1;
  float* O = out + ob;
  const int gb = b0 + lb;
#pragma unroll
  for (int i = 0; i < 4; ++i) {
    const int row0 = m0 + wm * 64 + i * 16 + (l >> 4) * 4;
#pragma unroll
    for (int j = 0; j < 4; ++j) {
      const int cg = nt * 128 + wn * 64 + j * 16 + (l & 15);
#pragma unroll
      for (int r = 0; r < 4; ++r) {
        const int row = row0 + r;
        if (row < 196 && cg < Ci)
          O[((size_t)gb * 196 + row) * Ci + cg] = acc[i][j][r];
      }
    }
  }
}

// ---------------------------------------------------------------------------
extern "C" void kernel_launch(void* const* d_in, const int* in_sizes, int n_in,
                              void* d_out, int out_size, void* d_ws, size_t ws_size,
                              hipStream_t stream)
{
  const float* eall = (const float*)d_in[4];
  const float* Wq1 = (const float*)d_in[5];
  const float* Wq2 = (const float*)d_in[6];
  const float* Wq3 = (const float*)d_in[7];
  const float* Wq4 = (const float*)d_in[8];
  const float* Wk  = (const float*)d_in[9];
  const float* Wv  = (const float*)d_in[10];
  const float* Wo1 = (const float*)d_in[11];
  const float* Wo2 = (const float*)d_in[12];
  const float* Wo3 = (const float*)d_in[13];
  const float* Wo4 = (const float*)d_in[14];
  float* out = (float*)d_out;

  char* p = (char*)d_ws;
  auto alloc = [&](size_t bytes) -> void* {
    void* r = p; p += (bytes + 255) & ~(size_t)255; return r;
  };
  u16* embA = (u16*)alloc((size_t)7168 * 960 * 2);
  u16* WkB  = (u16*)alloc((size_t)4 * 1024 * 960 * 2);
  u16* WvB  = (u16*)alloc((size_t)4 * 1024 * 960 * 2);
  u16* WqB  = (u16*)alloc((size_t)4 * 352256 * 2);
  u16* WoB  = (u16*)alloc((size_t)352256 * 2);
  const size_t persist = (size_t)(p - (char*)d_ws);
  const size_t perLB = (size_t)1835008 * 2 + 2097152 + 458752 + 1835008 + 524288 + 64 + 2048;
  int Bc = 8;
  if      (persist + 32 * perLB <= ws_size) Bc = 32;
  else if (persist + 16 * perLB <= ws_size) Bc = 16;
  const int NB = Bc * 224;
  const int Z = Bc * 4;

  u16* Kt  = (u16*)alloc((size_t)4 * 1024 * NB * 2);
  u16* Qt  = (u16*)alloc((size_t)4 * 1024 * NB * 2);
  u16* V   = (u16*)alloc((size_t)Bc * 4 * 256 * 1024 * 2);
  u16* Gk  = (u16*)alloc((size_t)Bc * 4 * 256 * 224 * 2);
  u16* ctxh = (u16*)alloc((size_t)Bc * 4 * 229376 * 2);
  u16* ctx = (u16*)alloc((size_t)Bc * 262144 * 2);
  float* stats = (float*)alloc((size_t)Bc * 16 * 4);

  const dim3 blk(256);
  k_cvt<<<dim3(64480), blk, 0, stream>>>(eall, Wq1, Wq2, Wq3, Wq4, Wk, Wv,
                                         Wo1, Wo2, Wo3, Wo4,
                                         embA, WkB, WvB, WqB, WoB);

  const int NT = NB / 128;
  for (int b0 = 0; b0 < 32; b0 += Bc) {
    (void)hipMemsetAsync(stats, 0, (size_t)Bc * 16 * 4, stream);
    k_kt<<<dim3(NT, 8, 4), blk, 0, stream>>>(embA, WkB, Kt, b0, NB);
    k_v <<<dim3(8, NT, 4), blk, 0, stream>>>(embA, WvB, V, b0, NB);
    k_q <<<dim3(NT, 8, 4), blk, 0, stream>>>(embA, WqB, Qt, b0, NB);
    k_gk<<<dim3(2, 2, Z), blk, 0, stream>>>(Kt, Gk, NB);
    k_qgq<<<dim3(2, 8, Z), blk, 0, stream>>>(Qt, Gk, stats, NB);
    k_att<<<dim3(Z, 15), blk, 0, stream>>>(Qt, Kt, V, stats, ctxh, NB);
    k_ctxred<<<dim3((Bc * 229376 / 8 + 255) / 256), blk, 0, stream>>>(ctxh, ctx, Bc);
    k_o <<<dim3(8, 2, Bc), blk, 0, stream>>>(ctx, WoB, out, b0);
  }
}

// Round 17
// 756.815 us; speedup vs baseline: 1.4279x; 1.0112x over previous
//
#include <hip/hip_runtime.h>
#include <math.h>

typedef __attribute__((ext_vector_type(8))) short bf16x8;   // 8 bf16 in 4 VGPRs
typedef __attribute__((ext_vector_type(4))) float f32x4;
typedef unsigned short u16;

__device__ __forceinline__ u16 f2bf(float f) {
  unsigned u = __float_as_uint(f);
  return (u16)((u + 0x7FFFu + ((u >> 16) & 1u)) >> 16);   // RNE
}
__device__ __forceinline__ float bf2f(u16 h) {
  return __uint_as_float(((unsigned)h) << 16);
}

__device__ __forceinline__ void gload16(const u16* g, void* lds) {
  __builtin_amdgcn_global_load_lds(
      (const __attribute__((address_space(1))) unsigned int*)g,
      (__attribute__((address_space(3))) unsigned int*)lds, 16, 0, 0);
}

// ---------------------------------------------------------------------------
// MFMA core BK=32 (proven): 128x128 tile, 256 threads. K mult of 32.
// Used by k_qgq (K=224). As/Bs: 128*32 u16.
// ---------------------------------------------------------------------------
__device__ __forceinline__ void mfma_core(
    const u16* __restrict__ A, int lda,
    const u16* __restrict__ B, int ldb,
    int K, f32x4 (&acc)[4][4], u16* As, u16* Bs)
{
  const int tid = threadIdx.x;
  const int l = tid & 63, w = tid >> 6;
  const int srow = w * 16 + (l >> 2);
  const int kel  = (l & 3) * 8;
  char* AsB = (char*)As + w * 1024;
  char* BsB = (char*)Bs + w * 1024;
  const u16* Ap  = A + (size_t)srow * lda + kel;
  const u16* Ap2 = A + (size_t)(srow + 64) * lda + kel;
  const u16* Bp  = B + (size_t)srow * ldb + kel;
  const u16* Bp2 = B + (size_t)(srow + 64) * ldb + kel;
  const int wm = w >> 1, wn = w & 1;
  const int aoff = (wm * 64 + (l & 15)) * 32 + (l >> 4) * 8;
  const int boff = (wn * 64 + (l & 15)) * 32 + (l >> 4) * 8;
  for (int kb = 0; kb < K; kb += 32) {
    __syncthreads();
    gload16(Ap + kb,  AsB);
    gload16(Ap2 + kb, AsB + 4096);
    gload16(Bp + kb,  BsB);
    gload16(Bp2 + kb, BsB + 4096);
    __syncthreads();
    bf16x8 av[4], bv[4];
#pragma unroll
    for (int i = 0; i < 4; ++i) {
      av[i] = *(const bf16x8*)(As + aoff + i * 16 * 32);
      bv[i] = *(const bf16x8*)(Bs + boff + i * 16 * 32);
    }
#pragma unroll
    for (int i = 0; i < 4; ++i)
#pragma unroll
      for (int j = 0; j < 4; ++j)
        acc[i][j] = __builtin_amdgcn_mfma_f32_16x16x32_bf16(av[i], bv[j], acc[i][j], 0, 0, 0);
  }
}

// ---------------------------------------------------------------------------
// MFMA core BK=64: 32 MFMAs per barrier pair. K mult of 64. As/Bs: 128*64 u16.
// ---------------------------------------------------------------------------
__device__ __forceinline__ void mfma_core64(
    const u16* __restrict__ A, int lda,
    const u16* __restrict__ B, int ldb,
    int K, f32x4 (&acc)[4][4], u16* As, u16* Bs)
{
  const int tid = threadIdx.x;
  const int l = tid & 63, w = tid >> 6;
  const int srow = w * 16 + (l >> 2);
  const int kel  = (l & 3) * 8;
  char* AsB = (char*)As + w * 1024;
  char* BsB = (char*)Bs + w * 1024;
  const u16* Ap  = A + (size_t)srow * lda + kel;
  const u16* Ap2 = A + (size_t)(srow + 64) * lda + kel;
  const u16* Bp  = B + (size_t)srow * ldb + kel;
  const u16* Bp2 = B + (size_t)(srow + 64) * ldb + kel;
  const int wm = w >> 1, wn = w & 1;
  const int aoff = (wm * 64 + (l & 15)) * 32 + (l >> 4) * 8;
  const int boff = (wn * 64 + (l & 15)) * 32 + (l >> 4) * 8;
  for (int kb = 0; kb < K; kb += 64) {
    __syncthreads();
    gload16(Ap + kb,       AsB);
    gload16(Ap2 + kb,      AsB + 4096);
    gload16(Ap + kb + 32,  AsB + 8192);
    gload16(Ap2 + kb + 32, AsB + 12288);
    gload16(Bp + kb,       BsB);
    gload16(Bp2 + kb,      BsB + 4096);
    gload16(Bp + kb + 32,  BsB + 8192);
    gload16(Bp2 + kb + 32, BsB + 12288);
    __syncthreads();
#pragma unroll
    for (int ks = 0; ks < 2; ++ks) {
      bf16x8 av[4], bv[4];
#pragma unroll
      for (int i = 0; i < 4; ++i) {
        av[i] = *(const bf16x8*)(As + ks * 4096 + aoff + i * 16 * 32);
        bv[i] = *(const bf16x8*)(Bs + ks * 4096 + boff + i * 16 * 32);
      }
#pragma unroll
      for (int i = 0; i < 4; ++i)
#pragma unroll
        for (int j = 0; j < 4; ++j)
          acc[i][j] = __builtin_amdgcn_mfma_f32_16x16x32_bf16(av[i], bv[j], acc[i][j], 0, 0, 0);
    }
  }
}

// ---------------------------------------------------------------------------
// One-shot pad/convert of all inputs (11 segments, hardcoded boundaries).
// ---------------------------------------------------------------------------
__global__ __launch_bounds__(256) void k_cvt(
    const float* __restrict__ eall,
    const float* __restrict__ Wq1, const float* __restrict__ Wq2,
    const float* __restrict__ Wq3, const float* __restrict__ Wq4,
    const float* __restrict__ Wk, const float* __restrict__ Wv,
    const float* __restrict__ Wo1, const float* __restrict__ Wo2,
    const float* __restrict__ Wo3, const float* __restrict__ Wo4,
    u16* __restrict__ embA, u16* __restrict__ WkB, u16* __restrict__ WvB,
    u16* __restrict__ WqB, u16* __restrict__ WoB)
{
  long long idx = (long long)blockIdx.x * 256 + threadIdx.x;
  const float* src; u16* dst; int srcR, dstR, C; long long stride, off, loc;
  if (idx < 6881280LL)       { loc = idx;               src=eall; dst=embA; srcR=196; dstR=224;  C=960; stride=215040; off=0; }
  else if (idx < 10813440LL) { loc = idx - 6881280LL;   src=Wk;   dst=WkB;  srcR=960; dstR=1024; C=960; stride=983040; off=0; }
  else if (idx < 14745600LL) { loc = idx - 10813440LL;  src=Wv;   dst=WvB;  srcR=960; dstR=1024; C=960; stride=983040; off=0; }
  else if (idx < 14778368LL) { loc = idx - 14745600LL;  src=Wq1;  dst=WqB;  srcR=64;  dstR=128;  C=64;  stride=352256; off=0; }
  else if (idx < 14843904LL) { loc = idx - 14778368LL;  src=Wq2;  dst=WqB;  srcR=128; dstR=128;  C=128; stride=352256; off=8192; }
  else if (idx < 15106048LL) { loc = idx - 14843904LL;  src=Wq3;  dst=WqB;  srcR=256; dstR=256;  C=256; stride=352256; off=24576; }
  else if (idx < 16154624LL) { loc = idx - 15106048LL;  src=Wq4;  dst=WqB;  srcR=512; dstR=512;  C=512; stride=352256; off=90112; }
  else if (idx < 16162816LL) { loc = idx - 16154624LL;  src=Wo1;  dst=WoB;  srcR=64;  dstR=128;  C=64;  stride=0; off=0; }
  else if (idx < 16179200LL) { loc = idx - 16162816LL;  src=Wo2;  dst=WoB;  srcR=128; dstR=128;  C=128; stride=0; off=8192; }
  else if (idx < 16244736LL) { loc = idx - 16179200LL;  src=Wo3;  dst=WoB;  srcR=256; dstR=256;  C=256; stride=0; off=24576; }
  else if (idx < 16506880LL) { loc = idx - 16244736LL;  src=Wo4;  dst=WoB;  srcR=512; dstR=512;  C=512; stride=0; off=90112; }
  else return;
  const long long per = (long long)dstR * C;
  const int g = (int)(loc / per);
  const int r2 = (int)(loc % per);
  const int rr = r2 / C, c = r2 - rr * C;
  const float v = (rr < srcR) ? src[((long long)g * srcR + rr) * C + c] : 0.f;
  dst[g * stride + off + (long long)rr * C + c] = f2bf(v);
}

// Kt[h][o(1024)][NB] = Wk[h] x embA^T
__global__ __launch_bounds__(256) void k_kt(const u16* __restrict__ embA,
    const u16* __restrict__ WkB, u16* __restrict__ Kt, int b0, int NB)
{
  __shared__ u16 As[128 * 64], Bs[128 * 64];
  const int h = blockIdx.z;
  const int m0 = blockIdx.y * 128, n0 = blockIdx.x * 128;
  const u16* A = WkB + (size_t)h * 1024 * 960 + (size_t)m0 * 960;
  const u16* B = embA + (size_t)(b0 * 224 + n0) * 960;
  f32x4 acc[4][4] = {};
  mfma_core64(A, 960, B, 960, 960, acc, As, Bs);
  const int tid = threadIdx.x, l = tid & 63, w = tid >> 6, wm = w >> 1, wn = w & 1;
  u16* C = Kt + (size_t)h * 1024 * NB;
#pragma unroll
  for (int i = 0; i < 4; ++i) {
    const int gm0 = m0 + wm * 64 + i * 16 + (l >> 4) * 4;
#pragma unroll
    for (int j = 0; j < 4; ++j) {
      const int n = n0 + wn * 64 + j * 16 + (l & 15);
#pragma unroll
      for (int r = 0; r < 4; ++r)
        C[(size_t)(gm0 + r) * NB + n] = f2bf(acc[i][j][r]);
    }
  }
}

// V[lb][h][n(256 pad)][o(1024)] = embA x Wv[h]^T
__global__ __launch_bounds__(256) void k_v(const u16* __restrict__ embA,
    const u16* __restrict__ WvB, u16* __restrict__ V, int b0, int NB)
{
  __shared__ u16 As[128 * 64], Bs[128 * 64];
  const int h = blockIdx.z;
  const int m0 = blockIdx.y * 128, n0 = blockIdx.x * 128;
  const u16* A = embA + (size_t)(b0 * 224 + m0) * 960;
  const u16* B = WvB + (size_t)h * 1024 * 960 + (size_t)n0 * 960;
  f32x4 acc[4][4] = {};
  mfma_core64(A, 960, B, 960, 960, acc, As, Bs);
  const int tid = threadIdx.x, l = tid & 63, w = tid >> 6, wm = w >> 1, wn = w & 1;
#pragma unroll
  for (int i = 0; i < 4; ++i) {
    const int t0 = m0 + wm * 64 + i * 16 + (l >> 4) * 4;
#pragma unroll
    for (int r = 0; r < 4; ++r) {
      const int t = t0 + r;
      const int lb = t / 224, n = t - lb * 224;
      u16* C = V + ((size_t)(lb * 4 + h) * 256 + n) * 1024;
#pragma unroll
      for (int j = 0; j < 4; ++j) {
        const int col = n0 + wn * 64 + j * 16 + (l & 15);
        C[col] = f2bf(acc[i][j][r]);
      }
    }
  }
}

// Qt[h][ccat(1024)][NB] = Wq_br[h] x emb_br^T  (branch slices read from embA)
__global__ __launch_bounds__(256) void k_q(const u16* __restrict__ embA,
    const u16* __restrict__ WqB, u16* __restrict__ Qt, int b0, int NB)
{
  __shared__ u16 As[128 * 64], Bs[128 * 64];
  const int h = blockIdx.z;
  const int y = blockIdx.y;
  const int br = (y == 0) ? 0 : (y == 1) ? 1 : (y < 4) ? 2 : 3;
  const int mt = (y <= 1) ? 0 : (y < 4) ? (y - 2) : (y - 4);
  const int Ci = 64 << br;
  const int coff = (br == 0) ? 0 : (br == 1) ? 64 : (br == 2) ? 192 : 448;
  const int wqo = (br == 0) ? 0 : (br == 1) ? 8192 : (br == 2) ? 24576 : 90112;
  const int n0 = blockIdx.x * 128;
  const u16* A = WqB + (size_t)h * 352256 + wqo + (size_t)mt * 128 * Ci;
  const u16* B = embA + (size_t)(b0 * 224 + n0) * 960 + coff;
  f32x4 acc[4][4] = {};
  mfma_core64(A, Ci, B, 960, Ci, acc, As, Bs);
  const int tid = threadIdx.x, l = tid & 63, w = tid >> 6, wm = w >> 1, wn = w & 1;
  u16* C = Qt + (size_t)h * 1024 * NB;
#pragma unroll
  for (int i = 0; i < 4; ++i) {
    const int lr0 = mt * 128 + wm * 64 + i * 16 + (l >> 4) * 4;
#pragma unroll
    for (int j = 0; j < 4; ++j) {
      const int n = n0 + wn * 64 + j * 16 + (l & 15);
#pragma unroll
      for (int r = 0; r < 4; ++r)
        if (lr0 + r < Ci)
          C[(size_t)(coff + lr0 + r) * NB + n] = f2bf(acc[i][j][r]);
    }
  }
}

// ---------------------------------------------------------------------------
// Gk[z][n'(256 rows, 224 used)][n 224] bf16 = sum_o Kt[o,n']Kt[o,n].
// ---------------------------------------------------------------------------
#define TS_LD 72
__global__ __launch_bounds__(256) void k_gk(const u16* __restrict__ Kt,
                                            u16* __restrict__ Gk, int NB)
{
  __shared__ u16 TsA[128 * TS_LD], TsB[128 * TS_LD];
  const int z = blockIdx.z, lb = z >> 2, h = z & 3;
  const int n0a = blockIdx.y * 96, n0b = blockIdx.x * 96;
  const u16* Kz = Kt + (size_t)h * 1024 * NB + lb * 224;
  const int tid = threadIdx.x, l = tid & 63, w = tid >> 6, wm = w >> 1, wn = w & 1;
  f32x4 acc[4][4] = {};
  for (int o0 = 0; o0 < 960; o0 += 64) {
    __syncthreads();
#pragma unroll
    for (int it = 0; it < 16; ++it) {
      const int e = it * 256 + tid;
      const int o = e >> 6, np = e & 63;
      const unsigned va = *(const unsigned*)(Kz + (size_t)(o0 + o) * NB + n0a + np * 2);
      const unsigned vb = *(const unsigned*)(Kz + (size_t)(o0 + o) * NB + n0b + np * 2);
      const int o8 = o >> 3, oe = o & 7;
      const int r0 = np * 2, r1 = r0 + 1;
      TsA[r0 * TS_LD + (((o8 ^ (r0 & 7)) << 3) | oe)] = (u16)(va & 0xffff);
      TsA[r1 * TS_LD + (((o8 ^ (r1 & 7)) << 3) | oe)] = (u16)(va >> 16);
      TsB[r0 * TS_LD + (((o8 ^ (r0 & 7)) << 3) | oe)] = (u16)(vb & 0xffff);
      TsB[r1 * TS_LD + (((o8 ^ (r1 & 7)) << 3) | oe)] = (u16)(vb >> 16);
    }
    __syncthreads();
#pragma unroll
    for (int ks = 0; ks < 2; ++ks) {
      bf16x8 av[4], bv[4];
#pragma unroll
      for (int i = 0; i < 4; ++i) {
        const int ra = wm * 64 + i * 16 + (l & 15);
        av[i] = *(const bf16x8*)(TsA + ra * TS_LD + (((ks * 4 + (l >> 4)) ^ (ra & 7)) << 3));
        const int rb = wn * 64 + i * 16 + (l & 15);
        bv[i] = *(const bf16x8*)(TsB + rb * TS_LD + (((ks * 4 + (l >> 4)) ^ (rb & 7)) << 3));
      }
#pragma unroll
      for (int i = 0; i < 4; ++i)
#pragma unroll
        for (int j = 0; j < 4; ++j)
          acc[i][j] = __builtin_amdgcn_mfma_f32_16x16x32_bf16(av[i], bv[j], acc[i][j], 0, 0, 0);
    }
  }
  u16* G = Gk + (size_t)z * 256 * 224;
#pragma unroll
  for (int i = 0; i < 4; ++i) {
    const int ra0 = n0a + wm * 64 + i * 16 + (l >> 4) * 4;
#pragma unroll
    for (int j = 0; j < 4; ++j) {
      const int cb = n0b + wn * 64 + j * 16 + (l & 15);
#pragma unroll
      for (int r = 0; r < 4; ++r)
        G[(size_t)(ra0 + r) * 224 + cb] = f2bf(acc[i][j][r]);
    }
  }
}

// ---------------------------------------------------------------------------
// sumsq per (z, branch): Y = Qt_tile x Gk (BK=32 core, K=224), dot with Qt.
// ---------------------------------------------------------------------------
__global__ __launch_bounds__(256) void k_qgq(const u16* __restrict__ Qt,
    const u16* __restrict__ Gk, float* __restrict__ stats, int NB)
{
  __shared__ u16 As[128 * 32], Bs[128 * 32];
  __shared__ float sb[4];
  const int z = blockIdx.z, lb = z >> 2, h = z & 3;
  const int m0 = blockIdx.y * 128;
  const int tx = blockIdx.x;
  const int tid = threadIdx.x;
  if (tid < 4) sb[tid] = 0.f;
  const u16* A = Qt + (size_t)h * 1024 * NB + (size_t)m0 * NB + lb * 224;
  const u16* B = Gk + (size_t)z * 256 * 224 + (size_t)(tx * 96) * 224;
  f32x4 acc[4][4] = {};
  mfma_core(A, NB, B, 224, 224, acc, As, Bs);
  const int l = tid & 63, w = tid >> 6, wm = w >> 1, wn = w & 1;
  const u16* Qbase = Qt + (size_t)h * 1024 * NB + lb * 224;
  float part[4]; int pbr[4]; bool ok[4];
#pragma unroll
  for (int i = 0; i < 4; ++i) {
    const int gm0 = m0 + wm * 64 + i * 16 + (l >> 4) * 4;
    pbr[i] = (gm0 < 64) ? 0 : (gm0 < 192) ? 1 : (gm0 < 448) ? 2 : 3;
    ok[i] = (gm0 < 960);
    float s = 0.f;
    if (ok[i]) {
#pragma unroll
      for (int j = 0; j < 4; ++j) {
        const int col = tx * 96 + wn * 64 + j * 16 + (l & 15);
        if (tx == 1 && col < 128) continue;
#pragma unroll
        for (int r = 0; r < 4; ++r)
          s += acc[i][j][r] * bf2f(Qbase[(size_t)(gm0 + r) * NB + col]);
      }
    }
    part[i] = s;
  }
  __syncthreads();
#pragma unroll
  for (int i = 0; i < 4; ++i)
    if (ok[i]) atomicAdd(&sb[pbr[i]], part[i]);
  __syncthreads();
  if (tid < 4) atomicAdd(stats + (size_t)z * 4 + tid, sb[tid]);
}

// ---------------------------------------------------------------------------
// Fused attention v3 + XCD-locality swizzle: 1-D grid Z*15; sid -> (z,ct) via
// xcd = sid&7, slot = sid>>3, z = xcd + 8*(slot/15), ct = slot%15.
// All 15 ct-blocks of a z share one XCD; only ~4-5 z's resident per XCD
// (<=3.7MB K+V, fits 4MB L2). Bijective for Z % 8 == 0 (Z in {32,64,128}).
// ---------------------------------------------------------------------------
#define KS_LD 232
#define VS_LD 72
#define PP_LD 72
__global__ __launch_bounds__(256, 2) void k_att(
    const u16* __restrict__ Qt, const u16* __restrict__ Kt,
    const u16* __restrict__ V, const float* __restrict__ stats,
    u16* __restrict__ ctxh, int NB)
{
  __shared__ u16 Ks[16384];          // 64 rows x 232 stride (+ tail pad)
  __shared__ u16 Vs[18432];          // 256 rows x 72 stride
  __shared__ u16 Ps[64 * PP_LD];
  __shared__ float rsum[64];
  const int sid = blockIdx.x;
  const int xcd = sid & 7, slot = sid >> 3;
  const int z = xcd + 8 * (slot / 15);
  const int ct = slot % 15;
  const int lb = z >> 2, h = z & 3;
  const int c0 = ct * 64;
  const int tid = threadIdx.x, l = tid & 63, w = tid >> 6;
  const int wm = w >> 1, wn = w & 1;
  const int br = (c0 < 64) ? 0 : (c0 < 192) ? 1 : (c0 < 448) ? 2 : 3;
  const float scale = 0.03227486121839514f;   // 1/sqrt(960)
  const float cnt = (float)(64 << br) * 960.f;
  const float var = stats[(size_t)z * 4 + br] * scale * scale / cnt;
  const float cs = scale * rsqrtf(var + 1e-5f);

  const u16* Qz = Qt + (size_t)h * 1024 * NB + (size_t)c0 * NB + lb * 224;
  const u16* Kz = Kt + (size_t)h * 1024 * NB + lb * 224;
  const u16* Vz = V + (size_t)z * 256 * 1024;

  bf16x8 qa[2][7];
#pragma unroll
  for (int i = 0; i < 2; ++i)
#pragma unroll
    for (int ks = 0; ks < 7; ++ks)
      qa[i][ks] = *(const bf16x8*)(Qz + (size_t)(wm * 32 + i * 16 + (l & 15)) * NB
                                   + ks * 32 + (l >> 4) * 8);
  if (tid < 64) rsum[tid] = 0.f;

  const u16* kp[8];
#pragma unroll
  for (int c = 0; c < 8; ++c) {
    const int e = (c * 4 + w) * 512 + l * 8;
    const int row = e / KS_LD, col = e - row * KS_LD;
    kp[c] = Kz + (size_t)row * NB + col;
  }
  const u16* vp[9];
#pragma unroll
  for (int c = 0; c < 9; ++c) {
    const int e = (c * 4 + w) * 512 + l * 8;
    const int row = e / VS_LD, col = e - row * VS_LD;
    vp[c] = Vz + (size_t)row * 1024 + col;
  }
  char* KsB = (char*)Ks + w * 1024;
  char* VsB = (char*)Vs + w * 1024;

  f32x4 cacc[7][2] = {};
  float rp[2][4] = {};

  for (int oc = 0; oc < 15; ++oc) {
    __syncthreads();
#pragma unroll
    for (int c = 0; c < 8; ++c) {
      gload16(kp[c], KsB + c * 4096);
      kp[c] += (size_t)64 * NB;
    }
#pragma unroll
    for (int c = 0; c < 9; ++c) {
      gload16(vp[c], VsB + c * 4096);
      vp[c] += 64;
    }
    __syncthreads();
    f32x4 sacc[2][2] = {};
#pragma unroll
    for (int ks = 0; ks < 7; ++ks) {
      bf16x8 kb[2];
#pragma unroll
      for (int j = 0; j < 2; ++j)
        kb[j] = *(const bf16x8*)(Ks + (wn * 32 + j * 16 + (l & 15)) * KS_LD
                                 + ks * 32 + (l >> 4) * 8);
#pragma unroll
      for (int i = 0; i < 2; ++i)
#pragma unroll
        for (int j = 0; j < 2; ++j)
          sacc[i][j] = __builtin_amdgcn_mfma_f32_16x16x32_bf16(qa[i][ks], kb[j], sacc[i][j], 0, 0, 0);
    }
#pragma unroll
    for (int i = 0; i < 2; ++i)
#pragma unroll
      for (int j = 0; j < 2; ++j)
#pragma unroll
        for (int r = 0; r < 4; ++r) {
          const float p = __expf(sacc[i][j][r] * cs);
          rp[i][r] += p;
          Ps[(wm * 32 + i * 16 + (l >> 4) * 4 + r) * PP_LD + wn * 32 + j * 16 + (l & 15)] = f2bf(p);
        }
    __syncthreads();
#pragma unroll
    for (int ks = 0; ks < 2; ++ks) {
      bf16x8 pv[2];
#pragma unroll
      for (int j = 0; j < 2; ++j)
        pv[j] = *(const bf16x8*)(Ps + (wn * 32 + j * 16 + (l & 15)) * PP_LD
                                 + ks * 32 + (l >> 4) * 8);
#pragma unroll
      for (int i2 = 0; i2 < 7; ++i2) {
        const bf16x8 av = *(const bf16x8*)(Vs + (wm * 112 + i2 * 16 + (l & 15)) * VS_LD
                                           + ks * 32 + (l >> 4) * 8);
#pragma unroll
        for (int j = 0; j < 2; ++j)
          cacc[i2][j] = __builtin_amdgcn_mfma_f32_16x16x32_bf16(av, pv[j], cacc[i2][j], 0, 0, 0);
      }
    }
  }
  __syncthreads();
#pragma unroll
  for (int i = 0; i < 2; ++i)
#pragma unroll
    for (int r = 0; r < 4; ++r) {
      float v = rp[i][r];
      v += __shfl_xor(v, 1); v += __shfl_xor(v, 2);
      v += __shfl_xor(v, 4); v += __shfl_xor(v, 8);
      if ((l & 15) == 0) atomicAdd(&rsum[wm * 32 + i * 16 + (l >> 4) * 4 + r], v);
    }
  __syncthreads();
  float inv[2];
#pragma unroll
  for (int j = 0; j < 2; ++j)
    inv[j] = 1.f / rsum[wn * 32 + j * 16 + (l & 15)];

  u16* Cs = Ks;
  u16* dst = ctxh + (size_t)z * 229376 + c0;
#pragma unroll
  for (int pass = 0; pass < 2; ++pass) {
    if (wm == pass) {
#pragma unroll
      for (int i2 = 0; i2 < 7; ++i2)
#pragma unroll
        for (int j = 0; j < 2; ++j)
#pragma unroll
          for (int r = 0; r < 4; ++r)
            Cs[(i2 * 16 + (l >> 4) * 4 + r) * PP_LD + wn * 32 + j * 16 + (l & 15)]
                = f2bf(cacc[i2][j][r] * inv[j]);
    }
    __syncthreads();
    for (int u = tid; u < 112 * 8; u += 256) {
      const int row = u >> 3, c8 = u & 7;
      *(uint4*)(dst + (size_t)(pass * 112 + row) * 1024 + c8 * 8) =
          *(const uint4*)(Cs + row * PP_LD + c8 * 8);
    }
    __syncthreads();
  }
}

// ctx[lb][n][c] = bf16( 0.25 * sum_h ctxh[lb*4+h][n][c] )
__global__ __launch_bounds__(256) void k_ctxred(const u16* __restrict__ ctxh,
    u16* __restrict__ ctx, int Bc)
{
  const long long i8 = ((long long)blockIdx.x * 256 + threadIdx.x) * 8;
  if (i8 >= (long long)Bc * 229376) return;
  const int lb = (int)(i8 / 229376);
  const int off = (int)(i8 - (long long)lb * 229376);
  const u16* p = ctxh + (size_t)lb * 4 * 229376 + off;
  float s[8] = {};
#pragma unroll
  for (int h = 0; h < 4; ++h) {
    bf16x8 v = *(const bf16x8*)(p + (size_t)h * 229376);
#pragma unroll
    for (int i = 0; i < 8; ++i) s[i] += bf2f((u16)v[i]);
  }
  bf16x8 o;
#pragma unroll
  for (int i = 0; i < 8; ++i) o[i] = (short)f2bf(s[i] * 0.25f);
  *(bf16x8*)(ctx + (size_t)lb * 262144 + off) = o;
}

// O_br[b][n][c'] = ctx[b][n, coff:coff+Ci] . Wo_br^T   (f32 to d_out)
__global__ __launch_bounds__(256) void k_o(const u16* __restrict__ ctx,
    const u16* __restrict__ WoB, float* __restrict__ out, int b0)
{
  __shared__ u16 As[128 * 64], Bs[128 * 64];
  const int lb = blockIdx.z;
  const int x = blockIdx.x;
  const int br = (x == 0) ? 0 : (x == 1) ? 1 : (x < 4) ? 2 : 3;
  const int nt = (x <= 1) ? 0 : (x < 4) ? (x - 2) : (x - 4);
  const int Ci = 64 << br;
  const int coff = (br == 0) ? 0 : (br == 1) ? 64 : (br == 2) ? 192 : 448;
  const int woo = (br == 0) ? 0 : (br == 1) ? 8192 : (br == 2) ? 24576 : 90112;
  const long long ob = (br == 0) ? 0LL : (br == 1) ? 401408LL : (br == 2) ? 1204224LL : 2809856LL;
  const int m0 = blockIdx.y * 128;
  const u16* A = ctx + (size_t)lb * 262144 + (size_t)m0 * 1024 + coff;
  const u16* B = WoB + woo + (size_t)nt * 128 * Ci;
  f32x4 acc[4][4] = {};
  mfma_core64(A, 1024, B, Ci, Ci, acc, As, Bs);
  const int tid = threadIdx.x, l = tid & 63, w = tid >> 6, wm = w >> 1, wn = w & 1;
  float* O = out + ob;
  const int gb = b0 + lb;
#pragma unroll
  for (int i = 0; i < 4; ++i) {
    const int row0 = m0 + wm * 64 + i * 16 + (l >> 4) * 4;
#pragma unroll
    for (int j = 0; j < 4; ++j) {
      const int cg = nt * 128 + wn * 64 + j * 16 + (l & 15);
#pragma unroll
      for (int r = 0; r < 4; ++r) {
        const int row = row0 + r;
        if (row < 196 && cg < Ci)
          O[((size_t)gb * 196 + row) * Ci + cg] = acc[i][j][r];
      }
    }
  }
}

// ---------------------------------------------------------------------------
extern "C" void kernel_launch(void* const* d_in, const int* in_sizes, int n_in,
                              void* d_out, int out_size, void* d_ws, size_t ws_size,
                              hipStream_t stream)
{
  const float* eall = (const float*)d_in[4];
  const float* Wq1 = (const float*)d_in[5];
  const float* Wq2 = (const float*)d_in[6];
  const float* Wq3 = (const float*)d_in[7];
  const float* Wq4 = (const float*)d_in[8];
  const float* Wk  = (const float*)d_in[9];
  const float* Wv  = (const float*)d_in[10];
  const float* Wo1 = (const float*)d_in[11];
  const float* Wo2 = (const float*)d_in[12];
  const float* Wo3 = (const float*)d_in[13];
  const float* Wo4 = (const float*)d_in[14];
  float* out = (float*)d_out;

  char* p = (char*)d_ws;
  auto alloc = [&](size_t bytes) -> void* {
    void* r = p; p += (bytes + 255) & ~(size_t)255; return r;
  };
  u16* embA = (u16*)alloc((size_t)7168 * 960 * 2);
  u16* WkB  = (u16*)alloc((size_t)4 * 1024 * 960 * 2);
  u16* WvB  = (u16*)alloc((size_t)4 * 1024 * 960 * 2);
  u16* WqB  = (u16*)alloc((size_t)4 * 352256 * 2);
  u16* WoB  = (u16*)alloc((size_t)352256 * 2);
  const size_t persist = (size_t)(p - (char*)d_ws);
  const size_t perLB = (size_t)1835008 * 2 + 2097152 + 458752 + 1835008 + 524288 + 64 + 2048;
  int Bc = 8;
  if      (persist + 32 * perLB <= ws_size) Bc = 32;
  else if (persist + 16 * perLB <= ws_size) Bc = 16;
  const int NB = Bc * 224;
  const int Z = Bc * 4;

  u16* Kt  = (u16*)alloc((size_t)4 * 1024 * NB * 2);
  u16* Qt  = (u16*)alloc((size_t)4 * 1024 * NB * 2);
  u16* V   = (u16*)alloc((size_t)Bc * 4 * 256 * 1024 * 2);
  u16* Gk  = (u16*)alloc((size_t)Bc * 4 * 256 * 224 * 2);
  u16* ctxh = (u16*)alloc((size_t)Bc * 4 * 229376 * 2);
  u16* ctx = (u16*)alloc((size_t)Bc * 262144 * 2);
  float* stats = (float*)alloc((size_t)Bc * 16 * 4);

  const dim3 blk(256);
  k_cvt<<<dim3(64480), blk, 0, stream>>>(eall, Wq1, Wq2, Wq3, Wq4, Wk, Wv,
                                         Wo1, Wo2, Wo3, Wo4,
                                         embA, WkB, WvB, WqB, WoB);

  const int NT = NB / 128;
  for (int b0 = 0; b0 < 32; b0 += Bc) {
    (void)hipMemsetAsync(stats, 0, (size_t)Bc * 16 * 4, stream);
    k_kt<<<dim3(NT, 8, 4), blk, 0, stream>>>(embA, WkB, Kt, b0, NB);
    k_v <<<dim3(8, NT, 4), blk, 0, stream>>>(embA, WvB, V, b0, NB);
    k_q <<<dim3(NT, 8, 4), blk, 0, stream>>>(embA, WqB, Qt, b0, NB);
    k_gk<<<dim3(2, 2, Z), blk, 0, stream>>>(Kt, Gk, NB);
    k_qgq<<<dim3(2, 8, Z), blk, 0, stream>>>(Qt, Gk, stats, NB);
    k_att<<<dim3(Z * 15), blk, 0, stream>>>(Qt, Kt, V, stats, ctxh, NB);
    k_ctxred<<<dim3((Bc * 229376 / 8 + 255) / 256), blk, 0, stream>>>(ctxh, ctx, Bc);
    k_o <<<dim3(8, 2, Bc), blk, 0, stream>>>(ctx, WoB, out, b0);
  }
}

// Round 18
// 671.597 us; speedup vs baseline: 1.6091x; 1.1269x over previous
//
#include <hip/hip_runtime.h>
#include <math.h>

typedef __attribute__((ext_vector_type(8))) short bf16x8;   // 8 bf16 in 4 VGPRs
typedef __attribute__((ext_vector_type(4))) float f32x4;
typedef unsigned short u16;

__device__ __forceinline__ u16 f2bf(float f) {
  unsigned u = __float_as_uint(f);
  return (u16)((u + 0x7FFFu + ((u >> 16) & 1u)) >> 16);   // RNE
}
__device__ __forceinline__ float bf2f(u16 h) {
  return __uint_as_float(((unsigned)h) << 16);
}

__device__ __forceinline__ void gload16(const u16* g, void* lds) {
  __builtin_amdgcn_global_load_lds(
      (const __attribute__((address_space(1))) unsigned int*)g,
      (__attribute__((address_space(3))) unsigned int*)lds, 16, 0, 0);
}

// ---------------------------------------------------------------------------
// MFMA core BK=32 (proven): 128x128 tile, 256 threads. K mult of 32.
// Used by k_qgq (K=224). As/Bs: 128*32 u16.
// ---------------------------------------------------------------------------
__device__ __forceinline__ void mfma_core(
    const u16* __restrict__ A, int lda,
    const u16* __restrict__ B, int ldb,
    int K, f32x4 (&acc)[4][4], u16* As, u16* Bs)
{
  const int tid = threadIdx.x;
  const int l = tid & 63, w = tid >> 6;
  const int srow = w * 16 + (l >> 2);
  const int kel  = (l & 3) * 8;
  char* AsB = (char*)As + w * 1024;
  char* BsB = (char*)Bs + w * 1024;
  const u16* Ap  = A + (size_t)srow * lda + kel;
  const u16* Ap2 = A + (size_t)(srow + 64) * lda + kel;
  const u16* Bp  = B + (size_t)srow * ldb + kel;
  const u16* Bp2 = B + (size_t)(srow + 64) * ldb + kel;
  const int wm = w >> 1, wn = w & 1;
  const int aoff = (wm * 64 + (l & 15)) * 32 + (l >> 4) * 8;
  const int boff = (wn * 64 + (l & 15)) * 32 + (l >> 4) * 8;
  for (int kb = 0; kb < K; kb += 32) {
    __syncthreads();
    gload16(Ap + kb,  AsB);
    gload16(Ap2 + kb, AsB + 4096);
    gload16(Bp + kb,  BsB);
    gload16(Bp2 + kb, BsB + 4096);
    __syncthreads();
    bf16x8 av[4], bv[4];
#pragma unroll
    for (int i = 0; i < 4; ++i) {
      av[i] = *(const bf16x8*)(As + aoff + i * 16 * 32);
      bv[i] = *(const bf16x8*)(Bs + boff + i * 16 * 32);
    }
#pragma unroll
    for (int i = 0; i < 4; ++i)
#pragma unroll
      for (int j = 0; j < 4; ++j)
        acc[i][j] = __builtin_amdgcn_mfma_f32_16x16x32_bf16(av[i], bv[j], acc[i][j], 0, 0, 0);
  }
}

// ---------------------------------------------------------------------------
// MFMA core BK=64: 32 MFMAs per barrier pair. K mult of 64. As/Bs: 128*64 u16.
// ---------------------------------------------------------------------------
__device__ __forceinline__ void mfma_core64(
    const u16* __restrict__ A, int lda,
    const u16* __restrict__ B, int ldb,
    int K, f32x4 (&acc)[4][4], u16* As, u16* Bs)
{
  const int tid = threadIdx.x;
  const int l = tid & 63, w = tid >> 6;
  const int srow = w * 16 + (l >> 2);
  const int kel  = (l & 3) * 8;
  char* AsB = (char*)As + w * 1024;
  char* BsB = (char*)Bs + w * 1024;
  const u16* Ap  = A + (size_t)srow * lda + kel;
  const u16* Ap2 = A + (size_t)(srow + 64) * lda + kel;
  const u16* Bp  = B + (size_t)srow * ldb + kel;
  const u16* Bp2 = B + (size_t)(srow + 64) * ldb + kel;
  const int wm = w >> 1, wn = w & 1;
  const int aoff = (wm * 64 + (l & 15)) * 32 + (l >> 4) * 8;
  const int boff = (wn * 64 + (l & 15)) * 32 + (l >> 4) * 8;
  for (int kb = 0; kb < K; kb += 64) {
    __syncthreads();
    gload16(Ap + kb,       AsB);
    gload16(Ap2 + kb,      AsB + 4096);
    gload16(Ap + kb + 32,  AsB + 8192);
    gload16(Ap2 + kb + 32, AsB + 12288);
    gload16(Bp + kb,       BsB);
    gload16(Bp2 + kb,      BsB + 4096);
    gload16(Bp + kb + 32,  BsB + 8192);
    gload16(Bp2 + kb + 32, BsB + 12288);
    __syncthreads();
#pragma unroll
    for (int ks = 0; ks < 2; ++ks) {
      bf16x8 av[4], bv[4];
#pragma unroll
      for (int i = 0; i < 4; ++i) {
        av[i] = *(const bf16x8*)(As + ks * 4096 + aoff + i * 16 * 32);
        bv[i] = *(const bf16x8*)(Bs + ks * 4096 + boff + i * 16 * 32);
      }
#pragma unroll
      for (int i = 0; i < 4; ++i)
#pragma unroll
        for (int j = 0; j < 4; ++j)
          acc[i][j] = __builtin_amdgcn_mfma_f32_16x16x32_bf16(av[i], bv[j], acc[i][j], 0, 0, 0);
    }
  }
}

// ---------------------------------------------------------------------------
// One-shot pad/convert, vectorized x4 (float4 load -> 4xbf16 uint2 store).
// All segment sizes, C values, and row offsets are multiples of 4.
// ---------------------------------------------------------------------------
__global__ __launch_bounds__(256) void k_cvt(
    const float* __restrict__ eall,
    const float* __restrict__ Wq1, const float* __restrict__ Wq2,
    const float* __restrict__ Wq3, const float* __restrict__ Wq4,
    const float* __restrict__ Wk, const float* __restrict__ Wv,
    const float* __restrict__ Wo1, const float* __restrict__ Wo2,
    const float* __restrict__ Wo3, const float* __restrict__ Wo4,
    u16* __restrict__ embA, u16* __restrict__ WkB, u16* __restrict__ WvB,
    u16* __restrict__ WqB, u16* __restrict__ WoB)
{
  long long idx = ((long long)blockIdx.x * 256 + threadIdx.x) * 4;
  const float* src; u16* dst; int srcR, dstR, C; long long stride, off, loc;
  if (idx < 6881280LL)       { loc = idx;               src=eall; dst=embA; srcR=196; dstR=224;  C=960; stride=215040; off=0; }
  else if (idx < 10813440LL) { loc = idx - 6881280LL;   src=Wk;   dst=WkB;  srcR=960; dstR=1024; C=960; stride=983040; off=0; }
  else if (idx < 14745600LL) { loc = idx - 10813440LL;  src=Wv;   dst=WvB;  srcR=960; dstR=1024; C=960; stride=983040; off=0; }
  else if (idx < 14778368LL) { loc = idx - 14745600LL;  src=Wq1;  dst=WqB;  srcR=64;  dstR=128;  C=64;  stride=352256; off=0; }
  else if (idx < 14843904LL) { loc = idx - 14778368LL;  src=Wq2;  dst=WqB;  srcR=128; dstR=128;  C=128; stride=352256; off=8192; }
  else if (idx < 15106048LL) { loc = idx - 14843904LL;  src=Wq3;  dst=WqB;  srcR=256; dstR=256;  C=256; stride=352256; off=24576; }
  else if (idx < 16154624LL) { loc = idx - 15106048LL;  src=Wq4;  dst=WqB;  srcR=512; dstR=512;  C=512; stride=352256; off=90112; }
  else if (idx < 16162816LL) { loc = idx - 16154624LL;  src=Wo1;  dst=WoB;  srcR=64;  dstR=128;  C=64;  stride=0; off=0; }
  else if (idx < 16179200LL) { loc = idx - 16162816LL;  src=Wo2;  dst=WoB;  srcR=128; dstR=128;  C=128; stride=0; off=8192; }
  else if (idx < 16244736LL) { loc = idx - 16179200LL;  src=Wo3;  dst=WoB;  srcR=256; dstR=256;  C=256; stride=0; off=24576; }
  else if (idx < 16506880LL) { loc = idx - 16244736LL;  src=Wo4;  dst=WoB;  srcR=512; dstR=512;  C=512; stride=0; off=90112; }
  else return;
  const long long per = (long long)dstR * C;
  const int g = (int)(loc / per);
  const int r2 = (int)(loc % per);
  const int rr = r2 / C, c = r2 - rr * C;       // c multiple of 4
  uint2 o;
  if (rr < srcR) {
    const float4 v = *(const float4*)(src + ((long long)g * srcR + rr) * C + c);
    o.x = (unsigned)f2bf(v.x) | ((unsigned)f2bf(v.y) << 16);
    o.y = (unsigned)f2bf(v.z) | ((unsigned)f2bf(v.w) << 16);
  } else {
    o.x = 0u; o.y = 0u;
  }
  *(uint2*)(dst + g * stride + off + (long long)rr * C + c) = o;
}

// ---------------------------------------------------------------------------
// Merged producer: grid (NT, 8, 12); bz>>2 = role (0=Kt, 1=V, 2=Qt), bz&3 = h.
// All three roles are independent 128x128-tile BK=64 GEMMs reading embA.
// ---------------------------------------------------------------------------
__global__ __launch_bounds__(256) void k_kvq(const u16* __restrict__ embA,
    const u16* __restrict__ WkB, const u16* __restrict__ WvB,
    const u16* __restrict__ WqB, u16* __restrict__ Kt, u16* __restrict__ V,
    u16* __restrict__ Qt, int b0, int NB)
{
  __shared__ u16 As[128 * 64], Bs[128 * 64];
  const int role = blockIdx.z >> 2, h = blockIdx.z & 3;
  const int tid = threadIdx.x, l = tid & 63, w = tid >> 6, wm = w >> 1, wn = w & 1;

  if (role == 0) {
    // Kt[h][o(1024)][NB] = Wk[h] x embA^T
    const int m0 = blockIdx.y * 128, n0 = blockIdx.x * 128;
    const u16* A = WkB + (size_t)h * 1024 * 960 + (size_t)m0 * 960;
    const u16* B = embA + (size_t)(b0 * 224 + n0) * 960;
    f32x4 acc[4][4] = {};
    mfma_core64(A, 960, B, 960, 960, acc, As, Bs);
    u16* C = Kt + (size_t)h * 1024 * NB;
#pragma unroll
    for (int i = 0; i < 4; ++i) {
      const int gm0 = m0 + wm * 64 + i * 16 + (l >> 4) * 4;
#pragma unroll
      for (int j = 0; j < 4; ++j) {
        const int n = n0 + wn * 64 + j * 16 + (l & 15);
#pragma unroll
        for (int r = 0; r < 4; ++r)
          C[(size_t)(gm0 + r) * NB + n] = f2bf(acc[i][j][r]);
      }
    }
  } else if (role == 1) {
    // V[lb][h][n(256 pad)][o(1024)] = embA x Wv[h]^T  (x/y roles swapped)
    const int m0 = blockIdx.x * 128, n0 = blockIdx.y * 128;
    const u16* A = embA + (size_t)(b0 * 224 + m0) * 960;
    const u16* B = WvB + (size_t)h * 1024 * 960 + (size_t)n0 * 960;
    f32x4 acc[4][4] = {};
    mfma_core64(A, 960, B, 960, 960, acc, As, Bs);
#pragma unroll
    for (int i = 0; i < 4; ++i) {
      const int t0 = m0 + wm * 64 + i * 16 + (l >> 4) * 4;
#pragma unroll
      for (int r = 0; r < 4; ++r) {
        const int t = t0 + r;
        const int lb = t / 224, n = t - lb * 224;
        u16* C = V + ((size_t)(lb * 4 + h) * 256 + n) * 1024;
#pragma unroll
        for (int j = 0; j < 4; ++j) {
          const int col = n0 + wn * 64 + j * 16 + (l & 15);
          C[col] = f2bf(acc[i][j][r]);
        }
      }
    }
  } else {
    // Qt[h][ccat(1024)][NB] = Wq_br[h] x emb_br^T
    const int y = blockIdx.y;
    const int br = (y == 0) ? 0 : (y == 1) ? 1 : (y < 4) ? 2 : 3;
    const int mt = (y <= 1) ? 0 : (y < 4) ? (y - 2) : (y - 4);
    const int Ci = 64 << br;
    const int coff = (br == 0) ? 0 : (br == 1) ? 64 : (br == 2) ? 192 : 448;
    const int wqo = (br == 0) ? 0 : (br == 1) ? 8192 : (br == 2) ? 24576 : 90112;
    const int n0 = blockIdx.x * 128;
    const u16* A = WqB + (size_t)h * 352256 + wqo + (size_t)mt * 128 * Ci;
    const u16* B = embA + (size_t)(b0 * 224 + n0) * 960 + coff;
    f32x4 acc[4][4] = {};
    mfma_core64(A, Ci, B, 960, Ci, acc, As, Bs);
    u16* C = Qt + (size_t)h * 1024 * NB;
#pragma unroll
    for (int i = 0; i < 4; ++i) {
      const int lr0 = mt * 128 + wm * 64 + i * 16 + (l >> 4) * 4;
#pragma unroll
      for (int j = 0; j < 4; ++j) {
        const int n = n0 + wn * 64 + j * 16 + (l & 15);
#pragma unroll
        for (int r = 0; r < 4; ++r)
          if (lr0 + r < Ci)
            C[(size_t)(coff + lr0 + r) * NB + n] = f2bf(acc[i][j][r]);
      }
    }
  }
}

// ---------------------------------------------------------------------------
// Gk[z][n'(256 rows, 224 used)][n 224] bf16 = sum_o Kt[o,n']Kt[o,n].
// ---------------------------------------------------------------------------
#define TS_LD 72
__global__ __launch_bounds__(256) void k_gk(const u16* __restrict__ Kt,
                                            u16* __restrict__ Gk, int NB)
{
  __shared__ u16 TsA[128 * TS_LD], TsB[128 * TS_LD];
  const int z = blockIdx.z, lb = z >> 2, h = z & 3;
  const int n0a = blockIdx.y * 96, n0b = blockIdx.x * 96;
  const u16* Kz = Kt + (size_t)h * 1024 * NB + lb * 224;
  const int tid = threadIdx.x, l = tid & 63, w = tid >> 6, wm = w >> 1, wn = w & 1;
  f32x4 acc[4][4] = {};
  for (int o0 = 0; o0 < 960; o0 += 64) {
    __syncthreads();
#pragma unroll
    for (int it = 0; it < 16; ++it) {
      const int e = it * 256 + tid;
      const int o = e >> 6, np = e & 63;
      const unsigned va = *(const unsigned*)(Kz + (size_t)(o0 + o) * NB + n0a + np * 2);
      const unsigned vb = *(const unsigned*)(Kz + (size_t)(o0 + o) * NB + n0b + np * 2);
      const int o8 = o >> 3, oe = o & 7;
      const int r0 = np * 2, r1 = r0 + 1;
      TsA[r0 * TS_LD + (((o8 ^ (r0 & 7)) << 3) | oe)] = (u16)(va & 0xffff);
      TsA[r1 * TS_LD + (((o8 ^ (r1 & 7)) << 3) | oe)] = (u16)(va >> 16);
      TsB[r0 * TS_LD + (((o8 ^ (r0 & 7)) << 3) | oe)] = (u16)(vb & 0xffff);
      TsB[r1 * TS_LD + (((o8 ^ (r1 & 7)) << 3) | oe)] = (u16)(vb >> 16);
    }
    __syncthreads();
#pragma unroll
    for (int ks = 0; ks < 2; ++ks) {
      bf16x8 av[4], bv[4];
#pragma unroll
      for (int i = 0; i < 4; ++i) {
        const int ra = wm * 64 + i * 16 + (l & 15);
        av[i] = *(const bf16x8*)(TsA + ra * TS_LD + (((ks * 4 + (l >> 4)) ^ (ra & 7)) << 3));
        const int rb = wn * 64 + i * 16 + (l & 15);
        bv[i] = *(const bf16x8*)(TsB + rb * TS_LD + (((ks * 4 + (l >> 4)) ^ (rb & 7)) << 3));
      }
#pragma unroll
      for (int i = 0; i < 4; ++i)
#pragma unroll
        for (int j = 0; j < 4; ++j)
          acc[i][j] = __builtin_amdgcn_mfma_f32_16x16x32_bf16(av[i], bv[j], acc[i][j], 0, 0, 0);
    }
  }
  u16* G = Gk + (size_t)z * 256 * 224;
#pragma unroll
  for (int i = 0; i < 4; ++i) {
    const int ra0 = n0a + wm * 64 + i * 16 + (l >> 4) * 4;
#pragma unroll
    for (int j = 0; j < 4; ++j) {
      const int cb = n0b + wn * 64 + j * 16 + (l & 15);
#pragma unroll
      for (int r = 0; r < 4; ++r)
        G[(size_t)(ra0 + r) * 224 + cb] = f2bf(acc[i][j][r]);
    }
  }
}

// ---------------------------------------------------------------------------
// sumsq per (z, branch): Y = Qt_tile x Gk (BK=32 core, K=224), dot with Qt.
// ---------------------------------------------------------------------------
__global__ __launch_bounds__(256) void k_qgq(const u16* __restrict__ Qt,
    const u16* __restrict__ Gk, float* __restrict__ stats, int NB)
{
  __shared__ u16 As[128 * 32], Bs[128 * 32];
  __shared__ float sb[4];
  const int z = blockIdx.z, lb = z >> 2, h = z & 3;
  const int m0 = blockIdx.y * 128;
  const int tx = blockIdx.x;
  const int tid = threadIdx.x;
  if (tid < 4) sb[tid] = 0.f;
  const u16* A = Qt + (size_t)h * 1024 * NB + (size_t)m0 * NB + lb * 224;
  const u16* B = Gk + (size_t)z * 256 * 224 + (size_t)(tx * 96) * 224;
  f32x4 acc[4][4] = {};
  mfma_core(A, NB, B, 224, 224, acc, As, Bs);
  const int l = tid & 63, w = tid >> 6, wm = w >> 1, wn = w & 1;
  const u16* Qbase = Qt + (size_t)h * 1024 * NB + lb * 224;
  float part[4]; int pbr[4]; bool ok[4];
#pragma unroll
  for (int i = 0; i < 4; ++i) {
    const int gm0 = m0 + wm * 64 + i * 16 + (l >> 4) * 4;
    pbr[i] = (gm0 < 64) ? 0 : (gm0 < 192) ? 1 : (gm0 < 448) ? 2 : 3;
    ok[i] = (gm0 < 960);
    float s = 0.f;
    if (ok[i]) {
#pragma unroll
      for (int j = 0; j < 4; ++j) {
        const int col = tx * 96 + wn * 64 + j * 16 + (l & 15);
        if (tx == 1 && col < 128) continue;
#pragma unroll
        for (int r = 0; r < 4; ++r)
          s += acc[i][j][r] * bf2f(Qbase[(size_t)(gm0 + r) * NB + col]);
      }
    }
    part[i] = s;
  }
  __syncthreads();
#pragma unroll
  for (int i = 0; i < 4; ++i)
    if (ok[i]) atomicAdd(&sb[pbr[i]], part[i]);
  __syncthreads();
  if (tid < 4) atomicAdd(stats + (size_t)z * 4 + tid, sb[tid]);
}

// ---------------------------------------------------------------------------
// Fused attention v3 + XCD-locality swizzle (R17, best measured).
// ---------------------------------------------------------------------------
#define KS_LD 232
#define VS_LD 72
#define PP_LD 72
__global__ __launch_bounds__(256, 2) void k_att(
    const u16* __restrict__ Qt, const u16* __restrict__ Kt,
    const u16* __restrict__ V, const float* __restrict__ stats,
    u16* __restrict__ ctxh, int NB)
{
  __shared__ u16 Ks[16384];
  __shared__ u16 Vs[18432];
  __shared__ u16 Ps[64 * PP_LD];
  __shared__ float rsum[64];
  const int sid = blockIdx.x;
  const int xcd = sid & 7, slot = sid >> 3;
  const int z = xcd + 8 * (slot / 15);
  const int ct = slot % 15;
  const int lb = z >> 2, h = z & 3;
  const int c0 = ct * 64;
  const int tid = threadIdx.x, l = tid & 63, w = tid >> 6;
  const int wm = w >> 1, wn = w & 1;
  const int br = (c0 < 64) ? 0 : (c0 < 192) ? 1 : (c0 < 448) ? 2 : 3;
  const float scale = 0.03227486121839514f;   // 1/sqrt(960)
  const float cnt = (float)(64 << br) * 960.f;
  const float var = stats[(size_t)z * 4 + br] * scale * scale / cnt;
  const float cs = scale * rsqrtf(var + 1e-5f);

  const u16* Qz = Qt + (size_t)h * 1024 * NB + (size_t)c0 * NB + lb * 224;
  const u16* Kz = Kt + (size_t)h * 1024 * NB + lb * 224;
  const u16* Vz = V + (size_t)z * 256 * 1024;

  bf16x8 qa[2][7];
#pragma unroll
  for (int i = 0; i < 2; ++i)
#pragma unroll
    for (int ks = 0; ks < 7; ++ks)
      qa[i][ks] = *(const bf16x8*)(Qz + (size_t)(wm * 32 + i * 16 + (l & 15)) * NB
                                   + ks * 32 + (l >> 4) * 8);
  if (tid < 64) rsum[tid] = 0.f;

  const u16* kp[8];
#pragma unroll
  for (int c = 0; c < 8; ++c) {
    const int e = (c * 4 + w) * 512 + l * 8;
    const int row = e / KS_LD, col = e - row * KS_LD;
    kp[c] = Kz + (size_t)row * NB + col;
  }
  const u16* vp[9];
#pragma unroll
  for (int c = 0; c < 9; ++c) {
    const int e = (c * 4 + w) * 512 + l * 8;
    const int row = e / VS_LD, col = e - row * VS_LD;
    vp[c] = Vz + (size_t)row * 1024 + col;
  }
  char* KsB = (char*)Ks + w * 1024;
  char* VsB = (char*)Vs + w * 1024;

  f32x4 cacc[7][2] = {};
  float rp[2][4] = {};

  for (int oc = 0; oc < 15; ++oc) {
    __syncthreads();
#pragma unroll
    for (int c = 0; c < 8; ++c) {
      gload16(kp[c], KsB + c * 4096);
      kp[c] += (size_t)64 * NB;
    }
#pragma unroll
    for (int c = 0; c < 9; ++c) {
      gload16(vp[c], VsB + c * 4096);
      vp[c] += 64;
    }
    __syncthreads();
    f32x4 sacc[2][2] = {};
#pragma unroll
    for (int ks = 0; ks < 7; ++ks) {
      bf16x8 kb[2];
#pragma unroll
      for (int j = 0; j < 2; ++j)
        kb[j] = *(const bf16x8*)(Ks + (wn * 32 + j * 16 + (l & 15)) * KS_LD
                                 + ks * 32 + (l >> 4) * 8);
#pragma unroll
      for (int i = 0; i < 2; ++i)
#pragma unroll
        for (int j = 0; j < 2; ++j)
          sacc[i][j] = __builtin_amdgcn_mfma_f32_16x16x32_bf16(qa[i][ks], kb[j], sacc[i][j], 0, 0, 0);
    }
#pragma unroll
    for (int i = 0; i < 2; ++i)
#pragma unroll
      for (int j = 0; j < 2; ++j)
#pragma unroll
        for (int r = 0; r < 4; ++r) {
          const float p = __expf(sacc[i][j][r] * cs);
          rp[i][r] += p;
          Ps[(wm * 32 + i * 16 + (l >> 4) * 4 + r) * PP_LD + wn * 32 + j * 16 + (l & 15)] = f2bf(p);
        }
    __syncthreads();
#pragma unroll
    for (int ks = 0; ks < 2; ++ks) {
      bf16x8 pv[2];
#pragma unroll
      for (int j = 0; j < 2; ++j)
        pv[j] = *(const bf16x8*)(Ps + (wn * 32 + j * 16 + (l & 15)) * PP_LD
                                 + ks * 32 + (l >> 4) * 8);
#pragma unroll
      for (int i2 = 0; i2 < 7; ++i2) {
        const bf16x8 av = *(const bf16x8*)(Vs + (wm * 112 + i2 * 16 + (l & 15)) * VS_LD
                                           + ks * 32 + (l >> 4) * 8);
#pragma unroll
        for (int j = 0; j < 2; ++j)
          cacc[i2][j] = __builtin_amdgcn_mfma_f32_16x16x32_bf16(av, pv[j], cacc[i2][j], 0, 0, 0);
      }
    }
  }
  __syncthreads();
#pragma unroll
  for (int i = 0; i < 2; ++i)
#pragma unroll
    for (int r = 0; r < 4; ++r) {
      float v = rp[i][r];
      v += __shfl_xor(v, 1); v += __shfl_xor(v, 2);
      v += __shfl_xor(v, 4); v += __shfl_xor(v, 8);
      if ((l & 15) == 0) atomicAdd(&rsum[wm * 32 + i * 16 + (l >> 4) * 4 + r], v);
    }
  __syncthreads();
  float inv[2];
#pragma unroll
  for (int j = 0; j < 2; ++j)
    inv[j] = 1.f / rsum[wn * 32 + j * 16 + (l & 15)];

  u16* Cs = Ks;
  u16* dst = ctxh + (size_t)z * 229376 + c0;
#pragma unroll
  for (int pass = 0; pass < 2; ++pass) {
    if (wm == pass) {
#pragma unroll
      for (int i2 = 0; i2 < 7; ++i2)
#pragma unroll
        for (int j = 0; j < 2; ++j)
#pragma unroll
          for (int r = 0; r < 4; ++r)
            Cs[(i2 * 16 + (l >> 4) * 4 + r) * PP_LD + wn * 32 + j * 16 + (l & 15)]
                = f2bf(cacc[i2][j][r] * inv[j]);
    }
    __syncthreads();
    for (int u = tid; u < 112 * 8; u += 256) {
      const int row = u >> 3, c8 = u & 7;
      *(uint4*)(dst + (size_t)(pass * 112 + row) * 1024 + c8 * 8) =
          *(const uint4*)(Cs + row * PP_LD + c8 * 8);
    }
    __syncthreads();
  }
}

// ctx[lb][n][c] = bf16( 0.25 * sum_h ctxh[lb*4+h][n][c] )
__global__ __launch_bounds__(256) void k_ctxred(const u16* __restrict__ ctxh,
    u16* __restrict__ ctx, int Bc)
{
  const long long i8 = ((long long)blockIdx.x * 256 + threadIdx.x) * 8;
  if (i8 >= (long long)Bc * 229376) return;
  const int lb = (int)(i8 / 229376);
  const int off = (int)(i8 - (long long)lb * 229376);
  const u16* p = ctxh + (size_t)lb * 4 * 229376 + off;
  float s[8] = {};
#pragma unroll
  for (int h = 0; h < 4; ++h) {
    bf16x8 v = *(const bf16x8*)(p + (size_t)h * 229376);
#pragma unroll
    for (int i = 0; i < 8; ++i) s[i] += bf2f((u16)v[i]);
  }
  bf16x8 o;
#pragma unroll
  for (int i = 0; i < 8; ++i) o[i] = (short)f2bf(s[i] * 0.25f);
  *(bf16x8*)(ctx + (size_t)lb * 262144 + off) = o;
}

// O_br[b][n][c'] = ctx[b][n, coff:coff+Ci] . Wo_br^T   (f32 to d_out)
__global__ __launch_bounds__(256) void k_o(const u16* __restrict__ ctx,
    const u16* __restrict__ WoB, float* __restrict__ out, int b0)
{
  __shared__ u16 As[128 * 64], Bs[128 * 64];
  const int lb = blockIdx.z;
  const int x = blockIdx.x;
  const int br = (x == 0) ? 0 : (x == 1) ? 1 : (x < 4) ? 2 : 3;
  const int nt = (x <= 1) ? 0 : (x < 4) ? (x - 2) : (x - 4);
  const int Ci = 64 << br;
  const int coff = (br == 0) ? 0 : (br == 1) ? 64 : (br == 2) ? 192 : 448;
  const int woo = (br == 0) ? 0 : (br == 1) ? 8192 : (br == 2) ? 24576 : 90112;
  const long long ob = (br == 0) ? 0LL : (br == 1) ? 401408LL : (br == 2) ? 1204224LL : 2809856LL;
  const int m0 = blockIdx.y * 128;
  const u16* A = ctx + (size_t)lb * 262144 + (size_t)m0 * 1024 + coff;
  const u16* B = WoB + woo + (size_t)nt * 128 * Ci;
  f32x4 acc[4][4] = {};
  mfma_core64(A, 1024, B, Ci, Ci, acc, As, Bs);
  const int tid = threadIdx.x, l = tid & 63, w = tid >> 6, wm = w >> 1, wn = w & 1;
  float* O = out + ob;
  const int gb = b0 + lb;
#pragma unroll
  for (int i = 0; i < 4; ++i) {
    const int row0 = m0 + wm * 64 + i * 16 + (l >> 4) * 4;
#pragma unroll
    for (int j = 0; j < 4; ++j) {
      const int cg = nt * 128 + wn * 64 + j * 16 + (l & 15);
#pragma unroll
      for (int r = 0; r < 4; ++r) {
        const int row = row0 + r;
        if (row < 196 && cg < Ci)
          O[((size_t)gb * 196 + row) * Ci + cg] = acc[i][j][r];
      }
    }
  }
}

// ---------------------------------------------------------------------------
extern "C" void kernel_launch(void* const* d_in, const int* in_sizes, int n_in,
                              void* d_out, int out_size, void* d_ws, size_t ws_size,
                              hipStream_t stream)
{
  const float* eall = (const float*)d_in[4];
  const float* Wq1 = (const float*)d_in[5];
  const float* Wq2 = (const float*)d_in[6];
  const float* Wq3 = (const float*)d_in[7];
  const float* Wq4 = (const float*)d_in[8];
  const float* Wk  = (const float*)d_in[9];
  const float* Wv  = (const float*)d_in[10];
  const float* Wo1 = (const float*)d_in[11];
  const float* Wo2 = (const float*)d_in[12];
  const float* Wo3 = (const float*)d_in[13];
  const float* Wo4 = (const float*)d_in[14];
  float* out = (float*)d_out;

  char* p = (char*)d_ws;
  auto alloc = [&](size_t bytes) -> void* {
    void* r = p; p += (bytes + 255) & ~(size_t)255; return r;
  };
  u16* embA = (u16*)alloc((size_t)7168 * 960 * 2);
  u16* WkB  = (u16*)alloc((size_t)4 * 1024 * 960 * 2);
  u16* WvB  = (u16*)alloc((size_t)4 * 1024 * 960 * 2);
  u16* WqB  = (u16*)alloc((size_t)4 * 352256 * 2);
  u16* WoB  = (u16*)alloc((size_t)352256 * 2);
  const size_t persist = (size_t)(p - (char*)d_ws);
  const size_t perLB = (size_t)1835008 * 2 + 2097152 + 458752 + 1835008 + 524288 + 64 + 2048;
  int Bc = 8;
  if      (persist + 32 * perLB <= ws_size) Bc = 32;
  else if (persist + 16 * perLB <= ws_size) Bc = 16;
  const int NB = Bc * 224;
  const int Z = Bc * 4;

  u16* Kt  = (u16*)alloc((size_t)4 * 1024 * NB * 2);
  u16* Qt  = (u16*)alloc((size_t)4 * 1024 * NB * 2);
  u16* V   = (u16*)alloc((size_t)Bc * 4 * 256 * 1024 * 2);
  u16* Gk  = (u16*)alloc((size_t)Bc * 4 * 256 * 224 * 2);
  u16* ctxh = (u16*)alloc((size_t)Bc * 4 * 229376 * 2);
  u16* ctx = (u16*)alloc((size_t)Bc * 262144 * 2);
  float* stats = (float*)alloc((size_t)Bc * 16 * 4);

  const dim3 blk(256);
  k_cvt<<<dim3(16120), blk, 0, stream>>>(eall, Wq1, Wq2, Wq3, Wq4, Wk, Wv,
                                         Wo1, Wo2, Wo3, Wo4,
                                         embA, WkB, WvB, WqB, WoB);

  const int NT = NB / 128;
  for (int b0 = 0; b0 < 32; b0 += Bc) {
    (void)hipMemsetAsync(stats, 0, (size_t)Bc * 16 * 4, stream);
    k_kvq<<<dim3(NT, 8, 12), blk, 0, stream>>>(embA, WkB, WvB, WqB,
                                               Kt, V, Qt, b0, NB);
    k_gk<<<dim3(2, 2, Z), blk, 0, stream>>>(Kt, Gk, NB);
    k_qgq<<<dim3(2, 8, Z), blk, 0, stream>>>(Qt, Gk, stats, NB);
    k_att<<<dim3(Z * 15), blk, 0, stream>>>(Qt, Kt, V, stats, ctxh, NB);
    k_ctxred<<<dim3((Bc * 229376 / 8 + 255) / 256), blk, 0, stream>>>(ctxh, ctx, Bc);
    k_o <<<dim3(8, 2, Bc), blk, 0, stream>>>(ctx, WoB, out, b0);
  }
}